// Round 9
// baseline (340.835 us; speedup 1.0000x reference)
//
#include <hip/hip_runtime.h>

typedef unsigned short u16;
typedef float f32x4 __attribute__((ext_vector_type(4)));
typedef __bf16 bf16x8 __attribute__((ext_vector_type(8)));
typedef u16 u16x8 __attribute__((ext_vector_type(8)));
typedef u16 u16x4 __attribute__((ext_vector_type(4)));

__device__ __forceinline__ u16 f2bf(float f) {
  union { float f; unsigned u; } v; v.f = f;
  unsigned r = (v.u + 0x7FFFu + ((v.u >> 16) & 1u)) >> 16;
  return (u16)r;
}
__device__ __forceinline__ unsigned cvtpk_bf16(float lo, float hi) {
  unsigned r;
  asm("v_cvt_pk_bf16_f32 %0, %1, %2" : "=v"(r) : "v"(lo), "v"(hi));
  return r;
}
__device__ __forceinline__ float wred_sum(float v) {
#pragma unroll
  for (int o = 32; o >= 1; o >>= 1) v += __shfl_xor(v, o);
  return v;
}

// ---------------------------------------------------------------------------
// bf16 MFMA GEMM: C = A[M,K] @ Bt[N,K]^T + bias. Outputs:
//  WF32: f32 [M][N];  WBF: bf16 [M][N];  WVT: bf16 head-transposed [bh][d][s]
// ---------------------------------------------------------------------------
template <int RELU, int WF32, int WBF, int WVT>
__global__ __launch_bounds__(256) void gemm_kernel(
    const u16* __restrict__ A, const u16* __restrict__ Bt,
    const float* __restrict__ bias, float* __restrict__ C,
    u16* __restrict__ Cbf, int M, int N, int K) {
  __shared__ u16 As[64 * 64];
  __shared__ u16 Bs[64 * 64];
  const int tid = threadIdx.x;
  const int lane = tid & 63;
  const int w = tid >> 6;
  const int m0 = blockIdx.x * 64;
  const int n0 = blockIdx.y * 64;
  const int wr = (w >> 1) * 32;
  const int wc = (w & 1) * 32;
  const int l15 = lane & 15, hi = lane >> 4;

  f32x4 acc[2][2] = {};

  for (int k0 = 0; k0 < K; k0 += 64) {
#pragma unroll
    for (int rep = 0; rep < 2; ++rep) {
      int idx = tid + rep * 256;
      int row = idx >> 3, c8 = idx & 7;
      int cs = ((c8 ^ (row & 7)) << 3);
      __builtin_amdgcn_global_load_lds(
          (const __attribute__((address_space(1))) void*)(A + (size_t)(m0 + row) * K + k0 + cs),
          (__attribute__((address_space(3))) void*)(&As[idx * 8]), 16, 0, 0);
      __builtin_amdgcn_global_load_lds(
          (const __attribute__((address_space(1))) void*)(Bt + (size_t)(n0 + row) * K + k0 + cs),
          (__attribute__((address_space(3))) void*)(&Bs[idx * 8]), 16, 0, 0);
    }
    __syncthreads();
#pragma unroll
    for (int kk = 0; kk < 2; ++kk) {
      int kb = (kk * 32 + (hi << 3)) << 1;
      bf16x8 af[2], bfr[2];
#pragma unroll
      for (int mf = 0; mf < 2; ++mf) {
        int m = wr + mf * 16 + l15;
        af[mf] = *(const bf16x8*)((const char*)As + m * 128 + (kb ^ ((m & 7) << 4)));
      }
#pragma unroll
      for (int nf = 0; nf < 2; ++nf) {
        int n = wc + nf * 16 + l15;
        bfr[nf] = *(const bf16x8*)((const char*)Bs + n * 128 + (kb ^ ((n & 7) << 4)));
      }
#pragma unroll
      for (int mf = 0; mf < 2; ++mf)
#pragma unroll
        for (int nf = 0; nf < 2; ++nf)
          acc[mf][nf] = __builtin_amdgcn_mfma_f32_16x16x32_bf16(af[mf], bfr[nf], acc[mf][nf], 0, 0, 0);
    }
    __syncthreads();
  }

#pragma unroll
  for (int mf = 0; mf < 2; ++mf)
#pragma unroll
    for (int nf = 0; nf < 2; ++nf) {
      int col = n0 + wc + nf * 16 + l15;
      float bia = bias[col];
      u16x4 tv;
#pragma unroll
      for (int r = 0; r < 4; ++r) {
        int row = m0 + wr + mf * 16 + (hi << 2) + r;
        float val = acc[mf][nf][r] + bia;
        if (RELU) val = fmaxf(val, 0.f);
        if (WF32) C[(size_t)row * N + col] = val;
        if (WBF) Cbf[(size_t)row * N + col] = f2bf(val);
        if (WVT) tv[r] = f2bf(val);
      }
      if (WVT) {
        int row0 = m0 + wr + mf * 16 + (hi << 2);
        size_t addr = (((size_t)(row0 >> 10) * 8 + (col >> 5)) * 32 + (col & 31)) * 1024 + (row0 & 1023);
        *(u16x4*)(Cbf + addr) = tv;
      }
    }
}

// ---------------------------------------------------------------------------
// Fused K+V projection: A[8192,256] @ WkvT[512,256]^T. Cols 0..255 -> qkbf
// (bf16 row-major, bias bk); cols 256..511 -> vT scatter (bias bv).
// vT must be a valid pointer (V half is always written).
// ---------------------------------------------------------------------------
__global__ __launch_bounds__(256) void gemm_kv_kernel(
    const u16* __restrict__ A, const u16* __restrict__ Bt,
    const float* __restrict__ biasK, const float* __restrict__ biasV,
    u16* __restrict__ qkbf, u16* __restrict__ vT, int M, int N, int K) {
  __shared__ u16 As[64 * 64];
  __shared__ u16 Bs[64 * 64];
  const int tid = threadIdx.x;
  const int lane = tid & 63;
  const int w = tid >> 6;
  const int m0 = blockIdx.x * 64;
  const int n0 = blockIdx.y * 64;
  const int wr = (w >> 1) * 32;
  const int wc = (w & 1) * 32;
  const int l15 = lane & 15, hi = lane >> 4;

  f32x4 acc[2][2] = {};

  for (int k0 = 0; k0 < K; k0 += 64) {
#pragma unroll
    for (int rep = 0; rep < 2; ++rep) {
      int idx = tid + rep * 256;
      int row = idx >> 3, c8 = idx & 7;
      int cs = ((c8 ^ (row & 7)) << 3);
      __builtin_amdgcn_global_load_lds(
          (const __attribute__((address_space(1))) void*)(A + (size_t)(m0 + row) * K + k0 + cs),
          (__attribute__((address_space(3))) void*)(&As[idx * 8]), 16, 0, 0);
      __builtin_amdgcn_global_load_lds(
          (const __attribute__((address_space(1))) void*)(Bt + (size_t)(n0 + row) * K + k0 + cs),
          (__attribute__((address_space(3))) void*)(&Bs[idx * 8]), 16, 0, 0);
    }
    __syncthreads();
#pragma unroll
    for (int kk = 0; kk < 2; ++kk) {
      int kb = (kk * 32 + (hi << 3)) << 1;
      bf16x8 af[2], bfr[2];
#pragma unroll
      for (int mf = 0; mf < 2; ++mf) {
        int m = wr + mf * 16 + l15;
        af[mf] = *(const bf16x8*)((const char*)As + m * 128 + (kb ^ ((m & 7) << 4)));
      }
#pragma unroll
      for (int nf = 0; nf < 2; ++nf) {
        int n = wc + nf * 16 + l15;
        bfr[nf] = *(const bf16x8*)((const char*)Bs + n * 128 + (kb ^ ((n & 7) << 4)));
      }
#pragma unroll
      for (int mf = 0; mf < 2; ++mf)
#pragma unroll
        for (int nf = 0; nf < 2; ++nf)
          acc[mf][nf] = __builtin_amdgcn_mfma_f32_16x16x32_bf16(af[mf], bfr[nf], acc[mf][nf], 0, 0, 0);
    }
    __syncthreads();
  }

  const bool isV = (n0 >= 256);
#pragma unroll
  for (int mf = 0; mf < 2; ++mf)
#pragma unroll
    for (int nf = 0; nf < 2; ++nf) {
      int col = n0 + wc + nf * 16 + l15;
      float bia = isV ? biasV[col - 256] : biasK[col];
      u16x4 tv;
#pragma unroll
      for (int r = 0; r < 4; ++r) {
        int row = m0 + wr + mf * 16 + (hi << 2) + r;
        float val = acc[mf][nf][r] + bia;
        if (!isV) qkbf[(size_t)row * 256 + col] = f2bf(val);
        tv[r] = f2bf(val);
      }
      if (isV) {
        int row0 = m0 + wr + mf * 16 + (hi << 2);
        int vc = col - 256;
        size_t addr = (((size_t)(row0 >> 10) * 8 + (vc >> 5)) * 32 + (vc & 31)) * 1024 + (row0 & 1023);
        *(u16x4*)(vT + addr) = tv;
      }
    }
}

// ---------------------------------------------------------------------------
// MFMA distance-decay attention, butterfly-balanced + 4-wave k-split:
// block = q-tiles (qp, 63-qp) of one (b,h) -> exactly 65 k-tiles, split
// across 4 waves (~16 each). Cross-wave per-row cumsum via per-context
// Z-prefix; PV partials reduced via per-context LDS buffers.
// log2-domain math; masked elements use l=-1000 => P=0 automatically.
// Pass B recomputes the QK MFMA (MFMA pipe idle; avoids register spill).
// ---------------------------------------------------------------------------
__global__ __launch_bounds__(256) void attn_mfma_kernel(
    const u16* __restrict__ qkbf, const u16* __restrict__ vT,
    u16* __restrict__ ao, const float* __restrict__ gam, int excl) {
  __shared__ float zbufA[4][16], zbufB[4][16];
  __shared__ float z2bufA[4][16], z2bufB[4][16];
  __shared__ float accbufA[8][4][64], accbufB[8][4][64];

  const int lane = threadIdx.x & 63, w = threadIdx.x >> 6;  // w in {0..3}
  const int qp = blockIdx.y, bh = blockIdx.x;
  const int b = bh >> 3, h = bh & 7;
  const int qtA = qp, qtB = 63 - qp;
  const int q0A = qtA * 16, q0B = qtB * 16;
  const int l15 = lane & 15, hi = lane >> 4;
  const int iA = q0A + l15, iB = q0B + l15;
  const float LOG2E = 1.4426950408889634f;
  const float g2 = -log1pf(__expf(gam[h])) * LOG2E;      // decay in log2 domain
  const float cscale = 0.17677669529663687f * LOG2E;     // 1/sqrt(32)*log2e
  const float CLIP2 = -16.609640474436812f;              // log2(1e-5)

  const u16* kbase = qkbf + (size_t)b * 1024 * 256 + h * 32;
  const u16* vbase = vT + (size_t)bh * 32 * 1024;
  const bf16x8 qfragA = *(const bf16x8*)(kbase + (size_t)iA * 256 + hi * 8);
  const bf16x8 qfragB = *(const bf16x8*)(kbase + (size_t)iB * 256 + hi * 8);

  const int mylimA = iA - excl, mylimB = iB - excl;
  const int ntA = qtA + 1, ntB = qtB + 1;   // k-tiles per q-tile
  const int ntT = ntA + ntB;                // 65, block-invariant
  const int C = (ntT + 3) >> 2;             // 17 tiles per wave
  const int g0 = w * C;
  const int g1 = (g0 + C < ntT) ? (g0 + C) : ntT;
  const int aS = g0 < ntA ? g0 : ntA;
  const int aE = g1 < ntA ? g1 : ntA;
  const int bS = (g0 > ntA ? g0 : ntA) - ntA;
  const int bE = (g1 > ntA ? g1 : ntA) - ntA;

  // QK -> log2-domain scores for one 16-k tile (mask last tile per row)
  auto calc_l = [&](const bf16x8& qf, int t, int lastT, int mylim, float* l) {
    bf16x8 kf = *(const bf16x8*)(kbase + (size_t)(t * 16 + l15) * 256 + hi * 8);
    f32x4 sA = {};
    sA = __builtin_amdgcn_mfma_f32_16x16x32_bf16(kf, qf, sA, 0, 0, 0);
    l[0] = sA[0] * cscale; l[1] = sA[1] * cscale;
    l[2] = sA[2] * cscale; l[3] = sA[3] * cscale;
    if (t == lastT) {                      // wave-uniform
      const int kb = t * 16 + hi * 4;
      l[0] = (kb + 0 <= mylim) ? l[0] : -1000.f;
      l[1] = (kb + 1 <= mylim) ? l[1] : -1000.f;
      l[2] = (kb + 2 <= mylim) ? l[2] : -1000.f;
      l[3] = (kb + 3 <= mylim) ? l[3] : -1000.f;
    }
  };

  // ---- pass A: chunk-partial Z per context ----
  float zA = 0.f, zB = 0.f;
  for (int t = aS; t < aE; ++t) {
    float l[4]; calc_l(qfragA, t, ntA - 1, mylimA, l);
    zA += (exp2f(l[0]) + exp2f(l[1])) + (exp2f(l[2]) + exp2f(l[3]));
  }
  for (int t = bS; t < bE; ++t) {
    float l[4]; calc_l(qfragB, t, ntB - 1, mylimB, l);
    zB += (exp2f(l[0]) + exp2f(l[1])) + (exp2f(l[2]) + exp2f(l[3]));
  }
  zA += __shfl_xor(zA, 16); zA += __shfl_xor(zA, 32);
  zB += __shfl_xor(zB, 16); zB += __shfl_xor(zB, 32);
  if (lane < 16) { zbufA[w][lane] = zA; zbufB[w][lane] = zB; }
  __syncthreads();

  float ZA = 0.f, ZB = 0.f, prefA = 0.f, prefB = 0.f;
#pragma unroll
  for (int ww = 0; ww < 4; ++ww) {
    const float za = zbufA[ww][l15], zb = zbufB[ww][l15];
    ZA += za; ZB += zb;
    if (ww < w) { prefA += za; prefB += zb; }
  }
  const float invZA = ZA > 0.f ? 1.f / ZA : 0.f;
  const float invZB = ZB > 0.f ? 1.f / ZB : 0.f;

  // cumsum -> decay -> P for one tile (e-domain carry, invZ in decay)
  auto sm4 = [&](const float* l, int kb, int irow, float Z, float invZ,
                 float& carry, float& z2) -> uint2 {
    const float e0 = exp2f(l[0]), e1 = exp2f(l[1]);
    const float e2 = exp2f(l[2]), e3 = exp2f(l[3]);
    const float cA = e0 + e1, cB2 = cA + e2, cC = cB2 + e3;
    float vsc = cC;
    float tmp = __shfl_up(vsc, 16); if (hi >= 1) vsc += tmp;
    tmp = __shfl_up(vsc, 32); if (hi >= 2) vsc += tmp;
    const float exg = vsc - cC;
    const float tot = __shfl(vsc, l15 + 48);
    const float cb = carry + exg;
    carry += tot;
    const float posb = (float)(irow - kb);
    const float r0 = (Z - (cb + e0)) * invZ;
    const float r1 = (Z - (cb + cA)) * invZ;
    const float r2 = (Z - (cb + cB2)) * invZ;
    const float r3 = (Z - (cb + cC)) * invZ;
    const float d20 = fmaxf(r0 * posb, 0.f);
    const float d21 = fmaxf(r1 * (posb - 1.f), 0.f);
    const float d22 = fmaxf(r2 * (posb - 2.f), 0.f);
    const float d23 = fmaxf(r3 * (posb - 3.f), 0.f);
    const float a0 = fmaxf(__builtin_amdgcn_sqrtf(d20) * g2, CLIP2);
    const float a1 = fmaxf(__builtin_amdgcn_sqrtf(d21) * g2, CLIP2);
    const float a2 = fmaxf(__builtin_amdgcn_sqrtf(d22) * g2, CLIP2);
    const float a3 = fmaxf(__builtin_amdgcn_sqrtf(d23) * g2, CLIP2);
    const float p0 = exp2f(l[0] * exp2f(a0));
    const float p1 = exp2f(l[1] * exp2f(a1));
    const float p2 = exp2f(l[2] * exp2f(a2));
    const float p3 = exp2f(l[3] * exp2f(a3));
    z2 += (p0 + p1) + (p2 + p3);
    uint2 r; r.x = cvtpk_bf16(p0, p1); r.y = cvtpk_bf16(p2, p3);
    return r;
  };

  // ---- pass B over one context's chunk: recompute QK, softmax2, PV ----
  auto run_ctx = [&](int s, int e, int lastT, int mylim, const bf16x8& qf,
                     int irow, float Z, float invZ, float& carry, float& z2,
                     f32x4& acc0, f32x4& acc1) {
    for (int t0 = s; t0 < e; t0 += 2) {
      const int t1 = t0 + 1;
      float la[4], lb[4];
      calc_l(qf, t0, lastT, mylim, la);
      const bool v1 = (t1 < e);            // wave-uniform
      if (v1) calc_l(qf, t1, lastT, mylim, lb);
      uint2 uA = sm4(la, t0 * 16 + hi * 4, irow, Z, invZ, carry, z2);
      uint2 uB = make_uint2(0u, 0u);
      if (v1) uB = sm4(lb, t1 * 16 + hi * 4, irow, Z, invZ, carry, z2);
      // regroup C-layout P^T (k=hi*4+r) into B-frag (k=hi*8..hi*8+7) over 32 k
      const int srcA = l15 + (((2 * hi) & 3) << 4);
      const int srcB = l15 + (((2 * hi + 1) & 3) << 4);
      unsigned a00 = (unsigned)__shfl((int)uA.x, srcA);
      unsigned a01 = (unsigned)__shfl((int)uB.x, srcA);
      unsigned a10 = (unsigned)__shfl((int)uA.y, srcA);
      unsigned a11 = (unsigned)__shfl((int)uB.y, srcA);
      unsigned b00 = (unsigned)__shfl((int)uA.x, srcB);
      unsigned b01 = (unsigned)__shfl((int)uB.x, srcB);
      unsigned b10 = (unsigned)__shfl((int)uA.y, srcB);
      unsigned b11 = (unsigned)__shfl((int)uB.y, srcB);
      const bool up = hi >= 2;
      union { unsigned u[4]; bf16x8 v; } pf;
      pf.u[0] = up ? a01 : a00;
      pf.u[1] = up ? a11 : a10;
      pf.u[2] = up ? b01 : b00;
      pf.u[3] = up ? b11 : b10;
      const int jb = t0 * 16;
      bf16x8 vf0 = *(const bf16x8*)(vbase + (size_t)l15 * 1024 + jb + hi * 8);
      bf16x8 vf1 = *(const bf16x8*)(vbase + (size_t)(16 + l15) * 1024 + jb + hi * 8);
      acc0 = __builtin_amdgcn_mfma_f32_16x16x32_bf16(vf0, pf.v, acc0, 0, 0, 0);
      acc1 = __builtin_amdgcn_mfma_f32_16x16x32_bf16(vf1, pf.v, acc1, 0, 0, 0);
    }
  };

  float carryA = prefA, z2A = 0.f, carryB = prefB, z2B = 0.f;
  f32x4 aA0 = {}, aA1 = {}, aB0 = {}, aB1 = {};
  run_ctx(aS, aE, ntA - 1, mylimA, qfragA, iA, ZA, invZA, carryA, z2A, aA0, aA1);
  run_ctx(bS, bE, ntB - 1, mylimB, qfragB, iB, ZB, invZB, carryB, z2B, aB0, aB1);

  z2A += __shfl_xor(z2A, 16); z2A += __shfl_xor(z2A, 32);
  z2B += __shfl_xor(z2B, 16); z2B += __shfl_xor(z2B, 32);
  if (lane < 16) { z2bufA[w][lane] = z2A; z2bufB[w][lane] = z2B; }
#pragma unroll
  for (int j = 0; j < 4; ++j) {
    accbufA[j][w][lane] = aA0[j];
    accbufA[4 + j][w][lane] = aA1[j];
    accbufB[j][w][lane] = aB0[j];
    accbufB[4 + j][w][lane] = aB1[j];
  }
  __syncthreads();

  if (w < 2) {
    const bool isA = (w == 0);                 // wave 0 -> A rows, wave 1 -> B
    float (*z2p)[16] = isA ? z2bufA : z2bufB;
    float (*accp)[4][64] = isA ? accbufA : accbufB;
    const int irow = isA ? iA : iB;
    const float z2t = z2p[0][l15] + z2p[1][l15] + z2p[2][l15] + z2p[3][l15];
    const float inv2 = z2t > 0.f ? 1.f / z2t : 0.f;  // 0 => excl row 0 (zero_pad)
    u16* aop = ao + ((size_t)(b * 1024 + irow)) * 256 + h * 32;
    float s0[4], s1[4];
#pragma unroll
    for (int j = 0; j < 4; ++j) {
      s0[j] = (accp[j][0][lane] + accp[j][1][lane] + accp[j][2][lane] + accp[j][3][lane]) * inv2;
      s1[j] = (accp[4 + j][0][lane] + accp[4 + j][1][lane] + accp[4 + j][2][lane] + accp[4 + j][3][lane]) * inv2;
    }
    uint2 o0, o1;
    o0.x = cvtpk_bf16(s0[0], s0[1]); o0.y = cvtpk_bf16(s0[2], s0[3]);
    o1.x = cvtpk_bf16(s1[0], s1[1]); o1.y = cvtpk_bf16(s1[2], s1[3]);
    *(uint2*)(aop + hi * 4) = o0;
    *(uint2*)(aop + 16 + hi * 4) = o1;
  }
}

// ---------------------------------------------------------------------------
__global__ __launch_bounds__(256) void add_ln_kernel(
    const float* __restrict__ res, const float* __restrict__ add,
    const float* __restrict__ g, const float* __restrict__ b,
    float* __restrict__ outf, u16* __restrict__ outb) {
  const int lane = threadIdx.x & 63, wid = threadIdx.x >> 6;
  const size_t row = (size_t)blockIdx.x * 4 + wid;
  const size_t base = row * 256 + lane * 4;
  float4 rv = *(const float4*)(res + base);
  float4 av = *(const float4*)(add + base);
  float x0 = rv.x + av.x, x1 = rv.y + av.y, x2 = rv.z + av.z, x3 = rv.w + av.w;
  float sm = wred_sum(x0 + x1 + x2 + x3);
  float mu = sm * (1.f / 256.f);
  float d0 = x0 - mu, d1 = x1 - mu, d2 = x2 - mu, d3 = x3 - mu;
  float vs = wred_sum(d0 * d0 + d1 * d1 + d2 * d2 + d3 * d3);
  float rs = rsqrtf(vs * (1.f / 256.f) + 1e-5f);
  float4 gv = *(const float4*)(g + lane * 4);
  float4 bv = *(const float4*)(b + lane * 4);
  float o0 = d0 * rs * gv.x + bv.x;
  float o1 = d1 * rs * gv.y + bv.y;
  float o2 = d2 * rs * gv.z + bv.z;
  float o3 = d3 * rs * gv.w + bv.w;
  float4 ov = {o0, o1, o2, o3};
  *(float4*)(outf + base) = ov;
  u16x4 wv; wv[0] = f2bf(o0); wv[1] = f2bf(o1); wv[2] = f2bf(o2); wv[3] = f2bf(o3);
  *(u16x4*)(outb + base) = wv;
}

__global__ __launch_bounds__(256) void cast_bf_kernel(
    const float* __restrict__ in, u16* __restrict__ out) {
  size_t i = ((size_t)blockIdx.x * 256 + threadIdx.x) * 8;
  float4 a = *(const float4*)(in + i);
  float4 c = *(const float4*)(in + i + 4);
  u16x8 o;
  o[0] = f2bf(a.x); o[1] = f2bf(a.y); o[2] = f2bf(a.z); o[3] = f2bf(a.w);
  o[4] = f2bf(c.x); o[5] = f2bf(c.y); o[6] = f2bf(c.z); o[7] = f2bf(c.w);
  *(u16x8*)(out + i) = o;
}

// Wt[z*dstStride + n*K + k] = bf16(W[z*K*N + k*N + n])
__global__ __launch_bounds__(256) void transpose_cast_kernel(
    const float* __restrict__ W, u16* __restrict__ Wt, int K, int N,
    int dstStride) {
  __shared__ float t[32][33];
  const size_t lo = (size_t)blockIdx.z * K * N;
  const size_t lod = (size_t)blockIdx.z * dstStride;
  int n0 = blockIdx.x * 32, k0 = blockIdx.y * 32;
  int tx = threadIdx.x, ty = threadIdx.y;  // 32 x 8
#pragma unroll
  for (int r = 0; r < 32; r += 8)
    t[ty + r][tx] = W[lo + (size_t)(k0 + ty + r) * N + n0 + tx];
  __syncthreads();
#pragma unroll
  for (int r = 0; r < 32; r += 8)
    Wt[lod + (size_t)(n0 + ty + r) * K + k0 + tx] = f2bf(t[tx][ty + r]);
}

// ---------------------------------------------------------------------------
extern "C" void kernel_launch(void* const* d_in, const int* in_sizes, int n_in,
                              void* d_out, int out_size, void* d_ws,
                              size_t ws_size, hipStream_t stream) {
  const float* q_embed = (const float*)d_in[0];
  const float* qa_embed = (const float*)d_in[1];
  const float* Wk = (const float*)d_in[2];
  const float* bk = (const float*)d_in[3];
  const float* Wv = (const float*)d_in[4];
  const float* bv = (const float*)d_in[5];
  const float* Wo = (const float*)d_in[6];
  const float* bo = (const float*)d_in[7];
  const float* gammas = (const float*)d_in[8];
  const float* ln1_g = (const float*)d_in[9];
  const float* ln1_b = (const float*)d_in[10];
  const float* W1 = (const float*)d_in[11];
  const float* b1 = (const float*)d_in[12];
  const float* W2 = (const float*)d_in[13];
  const float* b2 = (const float*)d_in[14];
  const float* ln2_g = (const float*)d_in[15];
  const float* ln2_b = (const float*)d_in[16];

  const size_t ACT_F32 = (size_t)8192 * 256 * 4;  // 8 MB
  const size_t ACT_BF = (size_t)8192 * 256 * 2;   // 4 MB
  char* p = (char*)d_ws;
  auto carve = [&](size_t bytes) {
    void* r = (void*)p;
    p += (bytes + 255) & ~(size_t)255;
    return r;
  };
  float* yb = (float*)carve(ACT_F32);
  float* xb = (float*)carve(ACT_F32);
  float* pof = (float*)carve(ACT_F32);
  u16* xbf = (u16*)carve(ACT_BF);
  u16* ybf = (u16*)carve(ACT_BF);
  u16* qkbf = (u16*)carve(ACT_BF);
  u16* vTb = (u16*)carve(ACT_BF);
  u16* aobf = (u16*)carve(ACT_BF);
  u16* hbf = (u16*)carve((size_t)8192 * 1024 * 2);  // 16 MB
  u16* Wkvt = (u16*)carve((size_t)3 * 131072 * 2);
  u16* Wot = (u16*)carve((size_t)3 * 65536 * 2);
  u16* W1t = (u16*)carve((size_t)3 * 262144 * 2);
  u16* W2t = (u16*)carve((size_t)3 * 262144 * 2);

  dim3 tb(32, 8);
  transpose_cast_kernel<<<dim3(8, 8, 3), tb, 0, stream>>>(Wk, Wkvt, 256, 256, 131072);
  transpose_cast_kernel<<<dim3(8, 8, 3), tb, 0, stream>>>(Wv, Wkvt + 65536, 256, 256, 131072);
  transpose_cast_kernel<<<dim3(8, 8, 3), tb, 0, stream>>>(Wo, Wot, 256, 256, 65536);
  transpose_cast_kernel<<<dim3(32, 8, 3), tb, 0, stream>>>(W1, W1t, 256, 1024, 262144);
  transpose_cast_kernel<<<dim3(8, 32, 3), tb, 0, stream>>>(W2, W2t, 1024, 256, 262144);
  cast_bf_kernel<<<1024, 256, 0, stream>>>(q_embed, xbf);
  cast_bf_kernel<<<1024, 256, 0, stream>>>(qa_embed, ybf);

  const dim3 gP(128, 4), gF(128, 16), gKV(128, 8);
  const dim3 gA(64, 32);

  // ---- block 0: layer 0, y = qa, incl mask, FFN ----
  gemm_kv_kernel<<<gKV, 256, 0, stream>>>(ybf, Wkvt, bk, bv, qkbf, vTb, 8192, 512, 256);
  attn_mfma_kernel<<<gA, 256, 0, stream>>>(qkbf, vTb, aobf, gammas, 0);
  gemm_kernel<0, 1, 0, 0><<<gP, 256, 0, stream>>>(aobf, Wot, bo, pof, nullptr, 8192, 256, 256);
  add_ln_kernel<<<2048, 256, 0, stream>>>(qa_embed, pof, ln1_g, ln1_b, yb, ybf);
  gemm_kernel<1, 0, 1, 0><<<gF, 256, 0, stream>>>(ybf, W1t, b1, nullptr, hbf, 8192, 1024, 256);
  gemm_kernel<0, 1, 0, 0><<<gP, 256, 0, stream>>>(hbf, W2t, b2, pof, nullptr, 8192, 256, 1024);
  add_ln_kernel<<<2048, 256, 0, stream>>>(yb, pof, ln2_g, ln2_b, yb, ybf);

  // ---- block 1: layer 1, x = q_embed, incl mask, no FFN ----
  gemm_kv_kernel<<<gKV, 256, 0, stream>>>(xbf, Wkvt + 131072, bk + 256, bv + 256, qkbf, vTb, 8192, 512, 256);
  attn_mfma_kernel<<<gA, 256, 0, stream>>>(qkbf, vTb, aobf, gammas + 8, 0);
  gemm_kernel<0, 1, 0, 0><<<gP, 256, 0, stream>>>(aobf, Wot + 65536, bo + 256, pof, nullptr, 8192, 256, 256);
  add_ln_kernel<<<2048, 256, 0, stream>>>(q_embed, pof, ln1_g + 256, ln1_b + 256, xb, xbf);

  // ---- block 2: layer 2, q/k from x, v from y, excl mask (zero_pad natural) ----
  // Fused KV writes V(x) into vTb (garbage), then the V(y) GEMM fully
  // overwrites vTb before attention reads it (same stream => ordered).
  gemm_kv_kernel<<<gKV, 256, 0, stream>>>(xbf, Wkvt + 262144, bk + 512, bv + 512, qkbf, vTb, 8192, 512, 256);
  gemm_kernel<0, 0, 0, 1><<<gP, 256, 0, stream>>>(ybf, Wkvt + 262144 + 65536, bv + 512, nullptr, vTb, 8192, 256, 256);
  attn_mfma_kernel<<<gA, 256, 0, stream>>>(qkbf, vTb, aobf, gammas + 16, 1);
  gemm_kernel<0, 1, 0, 0><<<gP, 256, 0, stream>>>(aobf, Wot + 131072, bo + 512, pof, nullptr, 8192, 256, 256);
  add_ln_kernel<<<2048, 256, 0, stream>>>(xb, pof, ln1_g + 512, ln1_b + 512, xb, xbf);
  gemm_kernel<1, 0, 1, 0><<<gF, 256, 0, stream>>>(xbf, W1t + 524288, b1 + 2048, nullptr, hbf, 8192, 1024, 256);
  gemm_kernel<0, 1, 0, 0><<<gP, 256, 0, stream>>>(hbf, W2t + 524288, b2 + 512, pof, nullptr, 8192, 256, 1024);
  add_ln_kernel<<<2048, 256, 0, stream>>>(xb, pof, ln2_g + 512, ln2_b + 512, (float*)d_out, xbf);
}

// Round 10
// 314.510 us; speedup vs baseline: 1.0837x; 1.0837x over previous
//
#include <hip/hip_runtime.h>

typedef unsigned short u16;
typedef float f32x4 __attribute__((ext_vector_type(4)));
typedef __bf16 bf16x8 __attribute__((ext_vector_type(8)));
typedef u16 u16x8 __attribute__((ext_vector_type(8)));
typedef u16 u16x4 __attribute__((ext_vector_type(4)));

__device__ __forceinline__ u16 f2bf(float f) {
  union { float f; unsigned u; } v; v.f = f;
  unsigned r = (v.u + 0x7FFFu + ((v.u >> 16) & 1u)) >> 16;
  return (u16)r;
}
__device__ __forceinline__ unsigned cvtpk_bf16(float lo, float hi) {
  unsigned r;
  asm("v_cvt_pk_bf16_f32 %0, %1, %2" : "=v"(r) : "v"(lo), "v"(hi));
  return r;
}
__device__ __forceinline__ float wred_sum(float v) {
#pragma unroll
  for (int o = 32; o >= 1; o >>= 1) v += __shfl_xor(v, o);
  return v;
}

// ---------------------------------------------------------------------------
// bf16 MFMA GEMM: C = A[M,K] @ Bt[N,K]^T + bias. Outputs:
//  WF32: f32 [M][N];  WBF: bf16 [M][N];  WVT: bf16 head-transposed [bh][d][s]
// ---------------------------------------------------------------------------
template <int RELU, int WF32, int WBF, int WVT>
__global__ __launch_bounds__(256) void gemm_kernel(
    const u16* __restrict__ A, const u16* __restrict__ Bt,
    const float* __restrict__ bias, float* __restrict__ C,
    u16* __restrict__ Cbf, int M, int N, int K) {
  __shared__ u16 As[64 * 64];
  __shared__ u16 Bs[64 * 64];
  const int tid = threadIdx.x;
  const int lane = tid & 63;
  const int w = tid >> 6;
  const int m0 = blockIdx.x * 64;
  const int n0 = blockIdx.y * 64;
  const int wr = (w >> 1) * 32;
  const int wc = (w & 1) * 32;
  const int l15 = lane & 15, hi = lane >> 4;

  f32x4 acc[2][2] = {};

  for (int k0 = 0; k0 < K; k0 += 64) {
#pragma unroll
    for (int rep = 0; rep < 2; ++rep) {
      int idx = tid + rep * 256;
      int row = idx >> 3, c8 = idx & 7;
      int cs = ((c8 ^ (row & 7)) << 3);
      __builtin_amdgcn_global_load_lds(
          (const __attribute__((address_space(1))) void*)(A + (size_t)(m0 + row) * K + k0 + cs),
          (__attribute__((address_space(3))) void*)(&As[idx * 8]), 16, 0, 0);
      __builtin_amdgcn_global_load_lds(
          (const __attribute__((address_space(1))) void*)(Bt + (size_t)(n0 + row) * K + k0 + cs),
          (__attribute__((address_space(3))) void*)(&Bs[idx * 8]), 16, 0, 0);
    }
    __syncthreads();
#pragma unroll
    for (int kk = 0; kk < 2; ++kk) {
      int kb = (kk * 32 + (hi << 3)) << 1;
      bf16x8 af[2], bfr[2];
#pragma unroll
      for (int mf = 0; mf < 2; ++mf) {
        int m = wr + mf * 16 + l15;
        af[mf] = *(const bf16x8*)((const char*)As + m * 128 + (kb ^ ((m & 7) << 4)));
      }
#pragma unroll
      for (int nf = 0; nf < 2; ++nf) {
        int n = wc + nf * 16 + l15;
        bfr[nf] = *(const bf16x8*)((const char*)Bs + n * 128 + (kb ^ ((n & 7) << 4)));
      }
#pragma unroll
      for (int mf = 0; mf < 2; ++mf)
#pragma unroll
        for (int nf = 0; nf < 2; ++nf)
          acc[mf][nf] = __builtin_amdgcn_mfma_f32_16x16x32_bf16(af[mf], bfr[nf], acc[mf][nf], 0, 0, 0);
    }
    __syncthreads();
  }

#pragma unroll
  for (int mf = 0; mf < 2; ++mf)
#pragma unroll
    for (int nf = 0; nf < 2; ++nf) {
      int col = n0 + wc + nf * 16 + l15;
      float bia = bias[col];
      u16x4 tv;
#pragma unroll
      for (int r = 0; r < 4; ++r) {
        int row = m0 + wr + mf * 16 + (hi << 2) + r;
        float val = acc[mf][nf][r] + bia;
        if (RELU) val = fmaxf(val, 0.f);
        if (WF32) C[(size_t)row * N + col] = val;
        if (WBF) Cbf[(size_t)row * N + col] = f2bf(val);
        if (WVT) tv[r] = f2bf(val);
      }
      if (WVT) {
        int row0 = m0 + wr + mf * 16 + (hi << 2);
        size_t addr = (((size_t)(row0 >> 10) * 8 + (col >> 5)) * 32 + (col & 31)) * 1024 + (row0 & 1023);
        *(u16x4*)(Cbf + addr) = tv;
      }
    }
}

// ---------------------------------------------------------------------------
// Fused K+V projection: A[8192,256] @ WkvT[512,256]^T. Cols 0..255 -> qkbf
// (bf16 row-major, bias bk); cols 256..511 -> vT scatter (bias bv).
// vT must be a valid pointer (V half is always written).
// ---------------------------------------------------------------------------
__global__ __launch_bounds__(256) void gemm_kv_kernel(
    const u16* __restrict__ A, const u16* __restrict__ Bt,
    const float* __restrict__ biasK, const float* __restrict__ biasV,
    u16* __restrict__ qkbf, u16* __restrict__ vT, int M, int N, int K) {
  __shared__ u16 As[64 * 64];
  __shared__ u16 Bs[64 * 64];
  const int tid = threadIdx.x;
  const int lane = tid & 63;
  const int w = tid >> 6;
  const int m0 = blockIdx.x * 64;
  const int n0 = blockIdx.y * 64;
  const int wr = (w >> 1) * 32;
  const int wc = (w & 1) * 32;
  const int l15 = lane & 15, hi = lane >> 4;

  f32x4 acc[2][2] = {};

  for (int k0 = 0; k0 < K; k0 += 64) {
#pragma unroll
    for (int rep = 0; rep < 2; ++rep) {
      int idx = tid + rep * 256;
      int row = idx >> 3, c8 = idx & 7;
      int cs = ((c8 ^ (row & 7)) << 3);
      __builtin_amdgcn_global_load_lds(
          (const __attribute__((address_space(1))) void*)(A + (size_t)(m0 + row) * K + k0 + cs),
          (__attribute__((address_space(3))) void*)(&As[idx * 8]), 16, 0, 0);
      __builtin_amdgcn_global_load_lds(
          (const __attribute__((address_space(1))) void*)(Bt + (size_t)(n0 + row) * K + k0 + cs),
          (__attribute__((address_space(3))) void*)(&Bs[idx * 8]), 16, 0, 0);
    }
    __syncthreads();
#pragma unroll
    for (int kk = 0; kk < 2; ++kk) {
      int kb = (kk * 32 + (hi << 3)) << 1;
      bf16x8 af[2], bfr[2];
#pragma unroll
      for (int mf = 0; mf < 2; ++mf) {
        int m = wr + mf * 16 + l15;
        af[mf] = *(const bf16x8*)((const char*)As + m * 128 + (kb ^ ((m & 7) << 4)));
      }
#pragma unroll
      for (int nf = 0; nf < 2; ++nf) {
        int n = wc + nf * 16 + l15;
        bfr[nf] = *(const bf16x8*)((const char*)Bs + n * 128 + (kb ^ ((n & 7) << 4)));
      }
#pragma unroll
      for (int mf = 0; mf < 2; ++mf)
#pragma unroll
        for (int nf = 0; nf < 2; ++nf)
          acc[mf][nf] = __builtin_amdgcn_mfma_f32_16x16x32_bf16(af[mf], bfr[nf], acc[mf][nf], 0, 0, 0);
    }
    __syncthreads();
  }

  const bool isV = (n0 >= 256);
#pragma unroll
  for (int mf = 0; mf < 2; ++mf)
#pragma unroll
    for (int nf = 0; nf < 2; ++nf) {
      int col = n0 + wc + nf * 16 + l15;
      float bia = isV ? biasV[col - 256] : biasK[col];
      u16x4 tv;
#pragma unroll
      for (int r = 0; r < 4; ++r) {
        int row = m0 + wr + mf * 16 + (hi << 2) + r;
        float val = acc[mf][nf][r] + bia;
        if (!isV) qkbf[(size_t)row * 256 + col] = f2bf(val);
        tv[r] = f2bf(val);
      }
      if (isV) {
        int row0 = m0 + wr + mf * 16 + (hi << 2);
        int vc = col - 256;
        size_t addr = (((size_t)(row0 >> 10) * 8 + (vc >> 5)) * 32 + (vc & 31)) * 1024 + (row0 & 1023);
        *(u16x4*)(vT + addr) = tv;
      }
    }
}

// ---------------------------------------------------------------------------
// MFMA distance-decay attention. R4/R5-proven structure: block = one 16-row
// q-tile of one (b,h), 4 waves each owning a contiguous quarter of the
// k-tile range; pass A's chunk Z partials double as cumsum prefixes.
// R7-proven log2-domain math (recompute QK in pass B; no register cache):
// masked elements get l=-1000 => p=0 automatically (pos<=0 -> te=1).
// Grid 64x64 big-work-first for dynamic block-level balancing.
// ---------------------------------------------------------------------------
__global__ __launch_bounds__(256) void attn_mfma_kernel(
    const u16* __restrict__ qkbf, const u16* __restrict__ vT,
    u16* __restrict__ ao, const float* __restrict__ gam, int excl) {
  __shared__ float zbuf[4][16];
  __shared__ float z2buf[4][16];
  __shared__ float accbuf[8][4][64];

  const int lane = threadIdx.x & 63, w = threadIdx.x >> 6;
  const int qt = 63 - blockIdx.y;  // big-work blocks dispatch first
  const int bh = blockIdx.x;
  const int b = bh >> 3, h = bh & 7;
  const int q0 = qt * 16;
  const int l15 = lane & 15, hi = lane >> 4;
  const int i = q0 + l15;  // this lane's q row
  const float LOG2E = 1.4426950408889634f;
  const float g2 = -log1pf(__expf(gam[h])) * LOG2E;      // decay in log2 domain
  const float cscale = 0.17677669529663687f * LOG2E;     // 1/sqrt(32)*log2e
  const float CLIP2 = -16.609640474436812f;              // log2(1e-5)

  const u16* kbase = qkbf + (size_t)b * 1024 * 256 + h * 32;
  const u16* vbase = vT + (size_t)bh * 32 * 1024;
  const bf16x8 qfrag = *(const bf16x8*)(kbase + (size_t)i * 256 + hi * 8);

  const int mylim = i - excl;            // valid k <= mylim
  const int jmax = q0 + 15 - excl;       // block-wide max valid k
  const int ntiles = (jmax >> 4) + 1;
  const int C = (ntiles + 3) >> 2;       // tiles per wave chunk
  const int c0 = w * C;
  const int tEnd = (c0 + C < ntiles) ? (c0 + C) : ntiles;
  const int count = (tEnd > c0) ? (tEnd - c0) : 0;

  // QK -> log2-domain scores for one 16-k tile (mask last tile per row)
  auto calc_l = [&](int t, float* l) {
    bf16x8 kf = *(const bf16x8*)(kbase + (size_t)(t * 16 + l15) * 256 + hi * 8);
    f32x4 sA = {};
    sA = __builtin_amdgcn_mfma_f32_16x16x32_bf16(kf, qfrag, sA, 0, 0, 0);
    l[0] = sA[0] * cscale; l[1] = sA[1] * cscale;
    l[2] = sA[2] * cscale; l[3] = sA[3] * cscale;
    if (t == ntiles - 1) {               // wave-uniform diagonal tile
      const int kb = t * 16 + hi * 4;
      l[0] = (kb + 0 <= mylim) ? l[0] : -1000.f;
      l[1] = (kb + 1 <= mylim) ? l[1] : -1000.f;
      l[2] = (kb + 2 <= mylim) ? l[2] : -1000.f;
      l[3] = (kb + 3 <= mylim) ? l[3] : -1000.f;
    }
  };

  // ---- pass A: chunk-partial Z ----
  float zacc = 0.f;
  for (int t = c0; t < tEnd; ++t) {
    float l[4]; calc_l(t, l);
    zacc += (exp2f(l[0]) + exp2f(l[1])) + (exp2f(l[2]) + exp2f(l[3]));
  }
  zacc += __shfl_xor(zacc, 16);
  zacc += __shfl_xor(zacc, 32);          // per-row chunk sum, replicated
  if (lane < 16) zbuf[w][lane] = zacc;
  __syncthreads();

  const float zc0 = zbuf[0][l15], zc1 = zbuf[1][l15];
  const float zc2 = zbuf[2][l15], zc3 = zbuf[3][l15];
  const float Z = zc0 + zc1 + zc2 + zc3;
  const float invZ = Z > 0.f ? 1.f / Z : 0.f;
  float prefix = 0.f;
  if (w > 0) prefix += zc0;
  if (w > 1) prefix += zc1;
  if (w > 2) prefix += zc2;

  // ---- pass B: e-domain cumsum -> decay -> softmax2 -> PV ----
  float carry = prefix, z2 = 0.f;
  f32x4 acc0 = {}, acc1 = {};

  // cumsum -> decay -> P for one tile (invZ folded into decay)
  auto sm4 = [&](const float* l, int kb) -> uint2 {
    const float e0 = exp2f(l[0]), e1 = exp2f(l[1]);
    const float e2 = exp2f(l[2]), e3 = exp2f(l[3]);
    const float cA = e0 + e1, cB2 = cA + e2, cC = cB2 + e3;
    float vsc = cC;
    float tmp = __shfl_up(vsc, 16); if (hi >= 1) vsc += tmp;
    tmp = __shfl_up(vsc, 32); if (hi >= 2) vsc += tmp;
    const float exg = vsc - cC;
    const float tot = __shfl(vsc, l15 + 48);
    const float cb = carry + exg;
    carry += tot;
    const float posb = (float)(i - kb);
    const float r0 = (Z - (cb + e0)) * invZ;
    const float r1 = (Z - (cb + cA)) * invZ;
    const float r2 = (Z - (cb + cB2)) * invZ;
    const float r3 = (Z - (cb + cC)) * invZ;
    const float d20 = fmaxf(r0 * posb, 0.f);
    const float d21 = fmaxf(r1 * (posb - 1.f), 0.f);
    const float d22 = fmaxf(r2 * (posb - 2.f), 0.f);
    const float d23 = fmaxf(r3 * (posb - 3.f), 0.f);
    const float a0 = fmaxf(__builtin_amdgcn_sqrtf(d20) * g2, CLIP2);
    const float a1 = fmaxf(__builtin_amdgcn_sqrtf(d21) * g2, CLIP2);
    const float a2 = fmaxf(__builtin_amdgcn_sqrtf(d22) * g2, CLIP2);
    const float a3 = fmaxf(__builtin_amdgcn_sqrtf(d23) * g2, CLIP2);
    const float p0 = exp2f(l[0] * exp2f(a0));
    const float p1 = exp2f(l[1] * exp2f(a1));
    const float p2 = exp2f(l[2] * exp2f(a2));
    const float p3 = exp2f(l[3] * exp2f(a3));
    z2 += (p0 + p1) + (p2 + p3);
    uint2 r; r.x = cvtpk_bf16(p0, p1); r.y = cvtpk_bf16(p2, p3);
    return r;
  };

  const int Cp = (count + 1) & ~1;
  for (int tl = 0; tl < Cp; tl += 2) {
    const int t0 = c0 + tl, t1 = t0 + 1;
    float la[4], lb[4];
    calc_l(t0, la);
    const bool v1 = (tl + 1 < count);    // wave-uniform
    if (v1) calc_l(t1, lb);
    uint2 uA = sm4(la, t0 * 16 + hi * 4);
    uint2 uB = make_uint2(0u, 0u);
    if (v1) uB = sm4(lb, t1 * 16 + hi * 4);
    // regroup C-layout P^T (k=hi*4+r) into B-frag (k=hi*8..hi*8+7) over 32 k
    const int srcA = l15 + (((2 * hi) & 3) << 4);
    const int srcB = l15 + (((2 * hi + 1) & 3) << 4);
    unsigned a00 = (unsigned)__shfl((int)uA.x, srcA);
    unsigned a01 = (unsigned)__shfl((int)uB.x, srcA);
    unsigned a10 = (unsigned)__shfl((int)uA.y, srcA);
    unsigned a11 = (unsigned)__shfl((int)uB.y, srcA);
    unsigned b00 = (unsigned)__shfl((int)uA.x, srcB);
    unsigned b01 = (unsigned)__shfl((int)uB.x, srcB);
    unsigned b10 = (unsigned)__shfl((int)uA.y, srcB);
    unsigned b11 = (unsigned)__shfl((int)uB.y, srcB);
    const bool up = hi >= 2;
    union { unsigned u[4]; bf16x8 v; } pf;
    pf.u[0] = up ? a01 : a00;
    pf.u[1] = up ? a11 : a10;
    pf.u[2] = up ? b01 : b00;
    pf.u[3] = up ? b11 : b10;
    const int jb = t0 * 16;
    bf16x8 vf0 = *(const bf16x8*)(vbase + (size_t)l15 * 1024 + jb + hi * 8);
    bf16x8 vf1 = *(const bf16x8*)(vbase + (size_t)(16 + l15) * 1024 + jb + hi * 8);
    acc0 = __builtin_amdgcn_mfma_f32_16x16x32_bf16(vf0, pf.v, acc0, 0, 0, 0);
    acc1 = __builtin_amdgcn_mfma_f32_16x16x32_bf16(vf1, pf.v, acc1, 0, 0, 0);
  }

  z2 += __shfl_xor(z2, 16);
  z2 += __shfl_xor(z2, 32);
  if (lane < 16) z2buf[w][lane] = z2;
#pragma unroll
  for (int j = 0; j < 4; ++j) {
    accbuf[j][w][lane] = acc0[j];
    accbuf[4 + j][w][lane] = acc1[j];
  }
  __syncthreads();

  if (w == 0) {
    const float z2t = z2buf[0][l15] + z2buf[1][l15] + z2buf[2][l15] + z2buf[3][l15];
    const float inv2 = z2t > 0.f ? 1.f / z2t : 0.f;  // 0 => excl row 0 (zero_pad)
    u16* aop = ao + ((size_t)(b * 1024 + i)) * 256 + h * 32;
    float s0[4], s1[4];
#pragma unroll
    for (int j = 0; j < 4; ++j) {
      s0[j] = (accbuf[j][0][lane] + accbuf[j][1][lane] + accbuf[j][2][lane] + accbuf[j][3][lane]) * inv2;
      s1[j] = (accbuf[4 + j][0][lane] + accbuf[4 + j][1][lane] + accbuf[4 + j][2][lane] + accbuf[4 + j][3][lane]) * inv2;
    }
    uint2 o0, o1;
    o0.x = cvtpk_bf16(s0[0], s0[1]); o0.y = cvtpk_bf16(s0[2], s0[3]);
    o1.x = cvtpk_bf16(s1[0], s1[1]); o1.y = cvtpk_bf16(s1[2], s1[3]);
    *(uint2*)(aop + hi * 4) = o0;
    *(uint2*)(aop + 16 + hi * 4) = o1;
  }
}

// ---------------------------------------------------------------------------
__global__ __launch_bounds__(256) void add_ln_kernel(
    const float* __restrict__ res, const float* __restrict__ add,
    const float* __restrict__ g, const float* __restrict__ b,
    float* __restrict__ outf, u16* __restrict__ outb) {
  const int lane = threadIdx.x & 63, wid = threadIdx.x >> 6;
  const size_t row = (size_t)blockIdx.x * 4 + wid;
  const size_t base = row * 256 + lane * 4;
  float4 rv = *(const float4*)(res + base);
  float4 av = *(const float4*)(add + base);
  float x0 = rv.x + av.x, x1 = rv.y + av.y, x2 = rv.z + av.z, x3 = rv.w + av.w;
  float sm = wred_sum(x0 + x1 + x2 + x3);
  float mu = sm * (1.f / 256.f);
  float d0 = x0 - mu, d1 = x1 - mu, d2 = x2 - mu, d3 = x3 - mu;
  float vs = wred_sum(d0 * d0 + d1 * d1 + d2 * d2 + d3 * d3);
  float rs = rsqrtf(vs * (1.f / 256.f) + 1e-5f);
  float4 gv = *(const float4*)(g + lane * 4);
  float4 bv = *(const float4*)(b + lane * 4);
  float o0 = d0 * rs * gv.x + bv.x;
  float o1 = d1 * rs * gv.y + bv.y;
  float o2 = d2 * rs * gv.z + bv.z;
  float o3 = d3 * rs * gv.w + bv.w;
  float4 ov = {o0, o1, o2, o3};
  *(float4*)(outf + base) = ov;
  u16x4 wv; wv[0] = f2bf(o0); wv[1] = f2bf(o1); wv[2] = f2bf(o2); wv[3] = f2bf(o3);
  *(u16x4*)(outb + base) = wv;
}

__global__ __launch_bounds__(256) void cast_bf_kernel(
    const float* __restrict__ in, u16* __restrict__ out) {
  size_t i = ((size_t)blockIdx.x * 256 + threadIdx.x) * 8;
  float4 a = *(const float4*)(in + i);
  float4 c = *(const float4*)(in + i + 4);
  u16x8 o;
  o[0] = f2bf(a.x); o[1] = f2bf(a.y); o[2] = f2bf(a.z); o[3] = f2bf(a.w);
  o[4] = f2bf(c.x); o[5] = f2bf(c.y); o[6] = f2bf(c.z); o[7] = f2bf(c.w);
  *(u16x8*)(out + i) = o;
}

// Wt[z*dstStride + n*K + k] = bf16(W[z*K*N + k*N + n])
__global__ __launch_bounds__(256) void transpose_cast_kernel(
    const float* __restrict__ W, u16* __restrict__ Wt, int K, int N,
    int dstStride) {
  __shared__ float t[32][33];
  const size_t lo = (size_t)blockIdx.z * K * N;
  const size_t lod = (size_t)blockIdx.z * dstStride;
  int n0 = blockIdx.x * 32, k0 = blockIdx.y * 32;
  int tx = threadIdx.x, ty = threadIdx.y;  // 32 x 8
#pragma unroll
  for (int r = 0; r < 32; r += 8)
    t[ty + r][tx] = W[lo + (size_t)(k0 + ty + r) * N + n0 + tx];
  __syncthreads();
#pragma unroll
  for (int r = 0; r < 32; r += 8)
    Wt[lod + (size_t)(n0 + ty + r) * K + k0 + tx] = f2bf(t[tx][ty + r]);
}

// ---------------------------------------------------------------------------
extern "C" void kernel_launch(void* const* d_in, const int* in_sizes, int n_in,
                              void* d_out, int out_size, void* d_ws,
                              size_t ws_size, hipStream_t stream) {
  const float* q_embed = (const float*)d_in[0];
  const float* qa_embed = (const float*)d_in[1];
  const float* Wk = (const float*)d_in[2];
  const float* bk = (const float*)d_in[3];
  const float* Wv = (const float*)d_in[4];
  const float* bv = (const float*)d_in[5];
  const float* Wo = (const float*)d_in[6];
  const float* bo = (const float*)d_in[7];
  const float* gammas = (const float*)d_in[8];
  const float* ln1_g = (const float*)d_in[9];
  const float* ln1_b = (const float*)d_in[10];
  const float* W1 = (const float*)d_in[11];
  const float* b1 = (const float*)d_in[12];
  const float* W2 = (const float*)d_in[13];
  const float* b2 = (const float*)d_in[14];
  const float* ln2_g = (const float*)d_in[15];
  const float* ln2_b = (const float*)d_in[16];

  const size_t ACT_F32 = (size_t)8192 * 256 * 4;  // 8 MB
  const size_t ACT_BF = (size_t)8192 * 256 * 2;   // 4 MB
  char* p = (char*)d_ws;
  auto carve = [&](size_t bytes) {
    void* r = (void*)p;
    p += (bytes + 255) & ~(size_t)255;
    return r;
  };
  float* yb = (float*)carve(ACT_F32);
  float* xb = (float*)carve(ACT_F32);
  float* pof = (float*)carve(ACT_F32);
  u16* xbf = (u16*)carve(ACT_BF);
  u16* ybf = (u16*)carve(ACT_BF);
  u16* qkbf = (u16*)carve(ACT_BF);
  u16* vTb = (u16*)carve(ACT_BF);
  u16* aobf = (u16*)carve(ACT_BF);
  u16* hbf = (u16*)carve((size_t)8192 * 1024 * 2);  // 16 MB
  u16* Wkvt = (u16*)carve((size_t)3 * 131072 * 2);
  u16* Wot = (u16*)carve((size_t)3 * 65536 * 2);
  u16* W1t = (u16*)carve((size_t)3 * 262144 * 2);
  u16* W2t = (u16*)carve((size_t)3 * 262144 * 2);

  dim3 tb(32, 8);
  transpose_cast_kernel<<<dim3(8, 8, 3), tb, 0, stream>>>(Wk, Wkvt, 256, 256, 131072);
  transpose_cast_kernel<<<dim3(8, 8, 3), tb, 0, stream>>>(Wv, Wkvt + 65536, 256, 256, 131072);
  transpose_cast_kernel<<<dim3(8, 8, 3), tb, 0, stream>>>(Wo, Wot, 256, 256, 65536);
  transpose_cast_kernel<<<dim3(32, 8, 3), tb, 0, stream>>>(W1, W1t, 256, 1024, 262144);
  transpose_cast_kernel<<<dim3(8, 32, 3), tb, 0, stream>>>(W2, W2t, 1024, 256, 262144);
  cast_bf_kernel<<<1024, 256, 0, stream>>>(q_embed, xbf);
  cast_bf_kernel<<<1024, 256, 0, stream>>>(qa_embed, ybf);

  const dim3 gP(128, 4), gF(128, 16), gKV(128, 8);
  const dim3 gA(64, 64);

  // ---- block 0: layer 0, y = qa, incl mask, FFN ----
  gemm_kv_kernel<<<gKV, 256, 0, stream>>>(ybf, Wkvt, bk, bv, qkbf, vTb, 8192, 512, 256);
  attn_mfma_kernel<<<gA, 256, 0, stream>>>(qkbf, vTb, aobf, gammas, 0);
  gemm_kernel<0, 1, 0, 0><<<gP, 256, 0, stream>>>(aobf, Wot, bo, pof, nullptr, 8192, 256, 256);
  add_ln_kernel<<<2048, 256, 0, stream>>>(qa_embed, pof, ln1_g, ln1_b, yb, ybf);
  gemm_kernel<1, 0, 1, 0><<<gF, 256, 0, stream>>>(ybf, W1t, b1, nullptr, hbf, 8192, 1024, 256);
  gemm_kernel<0, 1, 0, 0><<<gP, 256, 0, stream>>>(hbf, W2t, b2, pof, nullptr, 8192, 256, 1024);
  add_ln_kernel<<<2048, 256, 0, stream>>>(yb, pof, ln2_g, ln2_b, yb, ybf);

  // ---- block 1: layer 1, x = q_embed, incl mask, no FFN ----
  gemm_kv_kernel<<<gKV, 256, 0, stream>>>(xbf, Wkvt + 131072, bk + 256, bv + 256, qkbf, vTb, 8192, 512, 256);
  attn_mfma_kernel<<<gA, 256, 0, stream>>>(qkbf, vTb, aobf, gammas + 8, 0);
  gemm_kernel<0, 1, 0, 0><<<gP, 256, 0, stream>>>(aobf, Wot + 65536, bo + 256, pof, nullptr, 8192, 256, 256);
  add_ln_kernel<<<2048, 256, 0, stream>>>(q_embed, pof, ln1_g + 256, ln1_b + 256, xb, xbf);

  // ---- block 2: layer 2, q/k from x, v from y, excl mask (zero_pad natural) ----
  // Fused KV writes V(x) into vTb (garbage), then the V(y) GEMM fully
  // overwrites vTb before attention reads it (same stream => ordered).
  gemm_kv_kernel<<<gKV, 256, 0, stream>>>(xbf, Wkvt + 262144, bk + 512, bv + 512, qkbf, vTb, 8192, 512, 256);
  gemm_kernel<0, 0, 0, 1><<<gP, 256, 0, stream>>>(ybf, Wkvt + 262144 + 65536, bv + 512, nullptr, vTb, 8192, 256, 256);
  attn_mfma_kernel<<<gA, 256, 0, stream>>>(qkbf, vTb, aobf, gammas + 16, 1);
  gemm_kernel<0, 1, 0, 0><<<gP, 256, 0, stream>>>(aobf, Wot + 131072, bo + 512, pof, nullptr, 8192, 256, 256);
  add_ln_kernel<<<2048, 256, 0, stream>>>(xb, pof, ln1_g + 512, ln1_b + 512, xb, xbf);
  gemm_kernel<1, 0, 1, 0><<<gF, 256, 0, stream>>>(xbf, W1t + 524288, b1 + 2048, nullptr, hbf, 8192, 1024, 256);
  gemm_kernel<0, 1, 0, 0><<<gP, 256, 0, stream>>>(hbf, W2t + 524288, b2 + 512, pof, nullptr, 8192, 256, 1024);
  add_ln_kernel<<<2048, 256, 0, stream>>>(xb, pof, ln2_g + 512, ln2_b + 512, (float*)d_out, xbf);
}

// Round 11
// 313.743 us; speedup vs baseline: 1.0864x; 1.0024x over previous
//
#include <hip/hip_runtime.h>

typedef unsigned short u16;
typedef float f32x4 __attribute__((ext_vector_type(4)));
typedef __bf16 bf16x8 __attribute__((ext_vector_type(8)));
typedef u16 u16x8 __attribute__((ext_vector_type(8)));
typedef u16 u16x4 __attribute__((ext_vector_type(4)));

__device__ __forceinline__ u16 f2bf(float f) {
  union { float f; unsigned u; } v; v.f = f;
  unsigned r = (v.u + 0x7FFFu + ((v.u >> 16) & 1u)) >> 16;
  return (u16)r;
}
__device__ __forceinline__ float bf2f(u16 h) {
  union { unsigned u; float f; } v; v.u = ((unsigned)h) << 16;
  return v.f;
}
__device__ __forceinline__ unsigned cvtpk_bf16(float lo, float hi) {
  unsigned r;
  asm("v_cvt_pk_bf16_f32 %0, %1, %2" : "=v"(r) : "v"(lo), "v"(hi));
  return r;
}
__device__ __forceinline__ float wred_sum(float v) {
#pragma unroll
  for (int o = 32; o >= 1; o >>= 1) v += __shfl_xor(v, o);
  return v;
}

// ---------------------------------------------------------------------------
// bf16 MFMA GEMM, 64x64 tile: C = A[M,K] @ Bt[N,K]^T + bias.
//  WF32: f32 [M][N];  WBF: bf16 [M][N];  WVT: bf16 head-transposed [bh][d][s]
// ---------------------------------------------------------------------------
template <int RELU, int WF32, int WBF, int WVT>
__global__ __launch_bounds__(256) void gemm_kernel(
    const u16* __restrict__ A, const u16* __restrict__ Bt,
    const float* __restrict__ bias, float* __restrict__ C,
    u16* __restrict__ Cbf, int M, int N, int K) {
  __shared__ u16 As[64 * 64];
  __shared__ u16 Bs[64 * 64];
  const int tid = threadIdx.x;
  const int lane = tid & 63;
  const int w = tid >> 6;
  const int m0 = blockIdx.x * 64;
  const int n0 = blockIdx.y * 64;
  const int wr = (w >> 1) * 32;
  const int wc = (w & 1) * 32;
  const int l15 = lane & 15, hi = lane >> 4;

  f32x4 acc[2][2] = {};

  for (int k0 = 0; k0 < K; k0 += 64) {
#pragma unroll
    for (int rep = 0; rep < 2; ++rep) {
      int idx = tid + rep * 256;
      int row = idx >> 3, c8 = idx & 7;
      int cs = ((c8 ^ (row & 7)) << 3);
      __builtin_amdgcn_global_load_lds(
          (const __attribute__((address_space(1))) void*)(A + (size_t)(m0 + row) * K + k0 + cs),
          (__attribute__((address_space(3))) void*)(&As[idx * 8]), 16, 0, 0);
      __builtin_amdgcn_global_load_lds(
          (const __attribute__((address_space(1))) void*)(Bt + (size_t)(n0 + row) * K + k0 + cs),
          (__attribute__((address_space(3))) void*)(&Bs[idx * 8]), 16, 0, 0);
    }
    __syncthreads();
#pragma unroll
    for (int kk = 0; kk < 2; ++kk) {
      int kb = (kk * 32 + (hi << 3)) << 1;
      bf16x8 af[2], bfr[2];
#pragma unroll
      for (int mf = 0; mf < 2; ++mf) {
        int m = wr + mf * 16 + l15;
        af[mf] = *(const bf16x8*)((const char*)As + m * 128 + (kb ^ ((m & 7) << 4)));
      }
#pragma unroll
      for (int nf = 0; nf < 2; ++nf) {
        int n = wc + nf * 16 + l15;
        bfr[nf] = *(const bf16x8*)((const char*)Bs + n * 128 + (kb ^ ((n & 7) << 4)));
      }
#pragma unroll
      for (int mf = 0; mf < 2; ++mf)
#pragma unroll
        for (int nf = 0; nf < 2; ++nf)
          acc[mf][nf] = __builtin_amdgcn_mfma_f32_16x16x32_bf16(af[mf], bfr[nf], acc[mf][nf], 0, 0, 0);
    }
    __syncthreads();
  }

#pragma unroll
  for (int mf = 0; mf < 2; ++mf)
#pragma unroll
    for (int nf = 0; nf < 2; ++nf) {
      int col = n0 + wc + nf * 16 + l15;
      float bia = bias[col];
      u16x4 tv;
#pragma unroll
      for (int r = 0; r < 4; ++r) {
        int row = m0 + wr + mf * 16 + (hi << 2) + r;
        float val = acc[mf][nf][r] + bia;
        if (RELU) val = fmaxf(val, 0.f);
        if (WF32) C[(size_t)row * N + col] = val;
        if (WBF) Cbf[(size_t)row * N + col] = f2bf(val);
        if (WVT) tv[r] = f2bf(val);
      }
      if (WVT) {
        int row0 = m0 + wr + mf * 16 + (hi << 2);
        size_t addr = (((size_t)(row0 >> 10) * 8 + (col >> 5)) * 32 + (col & 31)) * 1024 + (row0 & 1023);
        *(u16x4*)(Cbf + addr) = tv;
      }
    }
}

// ---------------------------------------------------------------------------
// Wide bf16 MFMA GEMM, 64(M) x 128(N) tile, BK=64. bf16 row-major out, RELU.
// Used for W1 (N=1024): better MFMA:ds_read ratio than 64x64.
// ---------------------------------------------------------------------------
template <int RELU>
__global__ __launch_bounds__(256) void gemm_w_kernel(
    const u16* __restrict__ A, const u16* __restrict__ Bt,
    const float* __restrict__ bias, u16* __restrict__ Cbf,
    int M, int N, int K) {
  __shared__ u16 As[64 * 64];
  __shared__ u16 Bs[128 * 64];
  const int tid = threadIdx.x;
  const int lane = tid & 63;
  const int w = tid >> 6;
  const int m0 = blockIdx.x * 64;
  const int n0 = blockIdx.y * 128;
  const int wr = (w >> 1) * 32;   // 0 or 32
  const int wc = (w & 1) * 64;    // 0 or 64
  const int l15 = lane & 15, hi = lane >> 4;

  f32x4 acc[2][4] = {};

  for (int k0 = 0; k0 < K; k0 += 64) {
#pragma unroll
    for (int rep = 0; rep < 2; ++rep) {
      int idx = tid + rep * 256;
      int row = idx >> 3, c8 = idx & 7;
      int cs = ((c8 ^ (row & 7)) << 3);
      __builtin_amdgcn_global_load_lds(
          (const __attribute__((address_space(1))) void*)(A + (size_t)(m0 + row) * K + k0 + cs),
          (__attribute__((address_space(3))) void*)(&As[idx * 8]), 16, 0, 0);
    }
#pragma unroll
    for (int rep = 0; rep < 4; ++rep) {
      int idx = tid + rep * 256;
      int row = idx >> 3, c8 = idx & 7;
      int cs = ((c8 ^ (row & 7)) << 3);
      __builtin_amdgcn_global_load_lds(
          (const __attribute__((address_space(1))) void*)(Bt + (size_t)(n0 + row) * K + k0 + cs),
          (__attribute__((address_space(3))) void*)(&Bs[idx * 8]), 16, 0, 0);
    }
    __syncthreads();
#pragma unroll
    for (int kk = 0; kk < 2; ++kk) {
      int kb = (kk * 32 + (hi << 3)) << 1;
      bf16x8 af[2], bfr[4];
#pragma unroll
      for (int mf = 0; mf < 2; ++mf) {
        int m = wr + mf * 16 + l15;
        af[mf] = *(const bf16x8*)((const char*)As + m * 128 + (kb ^ ((m & 7) << 4)));
      }
#pragma unroll
      for (int nf = 0; nf < 4; ++nf) {
        int n = wc + nf * 16 + l15;
        bfr[nf] = *(const bf16x8*)((const char*)Bs + n * 128 + (kb ^ ((n & 7) << 4)));
      }
#pragma unroll
      for (int mf = 0; mf < 2; ++mf)
#pragma unroll
        for (int nf = 0; nf < 4; ++nf)
          acc[mf][nf] = __builtin_amdgcn_mfma_f32_16x16x32_bf16(af[mf], bfr[nf], acc[mf][nf], 0, 0, 0);
    }
    __syncthreads();
  }

#pragma unroll
  for (int mf = 0; mf < 2; ++mf)
#pragma unroll
    for (int nf = 0; nf < 4; ++nf) {
      int col = n0 + wc + nf * 16 + l15;
      float bia = bias[col];
#pragma unroll
      for (int r = 0; r < 4; ++r) {
        int row = m0 + wr + mf * 16 + (hi << 2) + r;
        float val = acc[mf][nf][r] + bia;
        if (RELU) val = fmaxf(val, 0.f);
        Cbf[(size_t)row * N + col] = f2bf(val);
      }
    }
}

// ---------------------------------------------------------------------------
// Fused K+V projection, wide 64x128 tile: A[8192,256] @ WkvT[512,256]^T.
// Cols 0..255 -> qkbf (bf16 row-major, bias bk); 256..511 -> vT scatter.
// Grid (M/64, 4). vT must be valid (V half always written).
// ---------------------------------------------------------------------------
__global__ __launch_bounds__(256) void gemm_kv_kernel(
    const u16* __restrict__ A, const u16* __restrict__ Bt,
    const float* __restrict__ biasK, const float* __restrict__ biasV,
    u16* __restrict__ qkbf, u16* __restrict__ vT, int M, int N, int K) {
  __shared__ u16 As[64 * 64];
  __shared__ u16 Bs[128 * 64];
  const int tid = threadIdx.x;
  const int lane = tid & 63;
  const int w = tid >> 6;
  const int m0 = blockIdx.x * 64;
  const int n0 = blockIdx.y * 128;
  const int wr = (w >> 1) * 32;
  const int wc = (w & 1) * 64;
  const int l15 = lane & 15, hi = lane >> 4;

  f32x4 acc[2][4] = {};

  for (int k0 = 0; k0 < K; k0 += 64) {
#pragma unroll
    for (int rep = 0; rep < 2; ++rep) {
      int idx = tid + rep * 256;
      int row = idx >> 3, c8 = idx & 7;
      int cs = ((c8 ^ (row & 7)) << 3);
      __builtin_amdgcn_global_load_lds(
          (const __attribute__((address_space(1))) void*)(A + (size_t)(m0 + row) * K + k0 + cs),
          (__attribute__((address_space(3))) void*)(&As[idx * 8]), 16, 0, 0);
    }
#pragma unroll
    for (int rep = 0; rep < 4; ++rep) {
      int idx = tid + rep * 256;
      int row = idx >> 3, c8 = idx & 7;
      int cs = ((c8 ^ (row & 7)) << 3);
      __builtin_amdgcn_global_load_lds(
          (const __attribute__((address_space(1))) void*)(Bt + (size_t)(n0 + row) * K + k0 + cs),
          (__attribute__((address_space(3))) void*)(&Bs[idx * 8]), 16, 0, 0);
    }
    __syncthreads();
#pragma unroll
    for (int kk = 0; kk < 2; ++kk) {
      int kb = (kk * 32 + (hi << 3)) << 1;
      bf16x8 af[2], bfr[4];
#pragma unroll
      for (int mf = 0; mf < 2; ++mf) {
        int m = wr + mf * 16 + l15;
        af[mf] = *(const bf16x8*)((const char*)As + m * 128 + (kb ^ ((m & 7) << 4)));
      }
#pragma unroll
      for (int nf = 0; nf < 4; ++nf) {
        int n = wc + nf * 16 + l15;
        bfr[nf] = *(const bf16x8*)((const char*)Bs + n * 128 + (kb ^ ((n & 7) << 4)));
      }
#pragma unroll
      for (int mf = 0; mf < 2; ++mf)
#pragma unroll
        for (int nf = 0; nf < 4; ++nf)
          acc[mf][nf] = __builtin_amdgcn_mfma_f32_16x16x32_bf16(af[mf], bfr[nf], acc[mf][nf], 0, 0, 0);
    }
    __syncthreads();
  }

#pragma unroll
  for (int mf = 0; mf < 2; ++mf)
#pragma unroll
    for (int nf = 0; nf < 4; ++nf) {
      int col = n0 + wc + nf * 16 + l15;
      const bool isV = (col >= 256);
      float bia = isV ? biasV[col - 256] : biasK[col];
      u16x4 tv;
#pragma unroll
      for (int r = 0; r < 4; ++r) {
        int row = m0 + wr + mf * 16 + (hi << 2) + r;
        float val = acc[mf][nf][r] + bia;
        if (!isV) qkbf[(size_t)row * 256 + col] = f2bf(val);
        tv[r] = f2bf(val);
      }
      if (isV) {
        int row0 = m0 + wr + mf * 16 + (hi << 2);
        int vc = col - 256;
        size_t addr = (((size_t)(row0 >> 10) * 8 + (vc >> 5)) * 32 + (vc & 31)) * 1024 + (row0 & 1023);
        *(u16x4*)(vT + addr) = tv;
      }
    }
}

// ---------------------------------------------------------------------------
// MFMA distance-decay attention (R10 structure, passing). Only change:
// V-fragment loads hoisted above the serial cumsum chain (carry-independent)
// so global latency hides under the scan.
// ---------------------------------------------------------------------------
__global__ __launch_bounds__(256) void attn_mfma_kernel(
    const u16* __restrict__ qkbf, const u16* __restrict__ vT,
    u16* __restrict__ ao, const float* __restrict__ gam, int excl) {
  __shared__ float zbuf[4][16];
  __shared__ float z2buf[4][16];
  __shared__ float accbuf[8][4][64];

  const int lane = threadIdx.x & 63, w = threadIdx.x >> 6;
  const int qt = 63 - blockIdx.y;  // big-work blocks dispatch first
  const int bh = blockIdx.x;
  const int b = bh >> 3, h = bh & 7;
  const int q0 = qt * 16;
  const int l15 = lane & 15, hi = lane >> 4;
  const int i = q0 + l15;  // this lane's q row
  const float LOG2E = 1.4426950408889634f;
  const float g2 = -log1pf(__expf(gam[h])) * LOG2E;      // decay in log2 domain
  const float cscale = 0.17677669529663687f * LOG2E;     // 1/sqrt(32)*log2e
  const float CLIP2 = -16.609640474436812f;              // log2(1e-5)

  const u16* kbase = qkbf + (size_t)b * 1024 * 256 + h * 32;
  const u16* vbase = vT + (size_t)bh * 32 * 1024;
  const bf16x8 qfrag = *(const bf16x8*)(kbase + (size_t)i * 256 + hi * 8);

  const int mylim = i - excl;            // valid k <= mylim
  const int jmax = q0 + 15 - excl;       // block-wide max valid k
  const int ntiles = (jmax >> 4) + 1;
  const int C = (ntiles + 3) >> 2;       // tiles per wave chunk
  const int c0 = w * C;
  const int tEnd = (c0 + C < ntiles) ? (c0 + C) : ntiles;
  const int count = (tEnd > c0) ? (tEnd - c0) : 0;

  // QK -> log2-domain scores for one 16-k tile (mask last tile per row)
  auto calc_l = [&](int t, float* l) {
    bf16x8 kf = *(const bf16x8*)(kbase + (size_t)(t * 16 + l15) * 256 + hi * 8);
    f32x4 sA = {};
    sA = __builtin_amdgcn_mfma_f32_16x16x32_bf16(kf, qfrag, sA, 0, 0, 0);
    l[0] = sA[0] * cscale; l[1] = sA[1] * cscale;
    l[2] = sA[2] * cscale; l[3] = sA[3] * cscale;
    if (t == ntiles - 1) {               // wave-uniform diagonal tile
      const int kb = t * 16 + hi * 4;
      l[0] = (kb + 0 <= mylim) ? l[0] : -1000.f;
      l[1] = (kb + 1 <= mylim) ? l[1] : -1000.f;
      l[2] = (kb + 2 <= mylim) ? l[2] : -1000.f;
      l[3] = (kb + 3 <= mylim) ? l[3] : -1000.f;
    }
  };

  // ---- pass A: chunk-partial Z ----
  float zacc = 0.f;
  for (int t = c0; t < tEnd; ++t) {
    float l[4]; calc_l(t, l);
    zacc += (exp2f(l[0]) + exp2f(l[1])) + (exp2f(l[2]) + exp2f(l[3]));
  }
  zacc += __shfl_xor(zacc, 16);
  zacc += __shfl_xor(zacc, 32);          // per-row chunk sum, replicated
  if (lane < 16) zbuf[w][lane] = zacc;
  __syncthreads();

  const float zc0 = zbuf[0][l15], zc1 = zbuf[1][l15];
  const float zc2 = zbuf[2][l15], zc3 = zbuf[3][l15];
  const float Z = zc0 + zc1 + zc2 + zc3;
  const float invZ = Z > 0.f ? 1.f / Z : 0.f;
  float prefix = 0.f;
  if (w > 0) prefix += zc0;
  if (w > 1) prefix += zc1;
  if (w > 2) prefix += zc2;

  // ---- pass B: e-domain cumsum -> decay -> softmax2 -> PV ----
  float carry = prefix, z2 = 0.f;
  f32x4 acc0 = {}, acc1 = {};

  auto sm4 = [&](const float* l, int kb) -> uint2 {
    const float e0 = exp2f(l[0]), e1 = exp2f(l[1]);
    const float e2 = exp2f(l[2]), e3 = exp2f(l[3]);
    const float cA = e0 + e1, cB2 = cA + e2, cC = cB2 + e3;
    float vsc = cC;
    float tmp = __shfl_up(vsc, 16); if (hi >= 1) vsc += tmp;
    tmp = __shfl_up(vsc, 32); if (hi >= 2) vsc += tmp;
    const float exg = vsc - cC;
    const float tot = __shfl(vsc, l15 + 48);
    const float cb = carry + exg;
    carry += tot;
    const float posb = (float)(i - kb);
    const float r0 = (Z - (cb + e0)) * invZ;
    const float r1 = (Z - (cb + cA)) * invZ;
    const float r2 = (Z - (cb + cB2)) * invZ;
    const float r3 = (Z - (cb + cC)) * invZ;
    const float d20 = fmaxf(r0 * posb, 0.f);
    const float d21 = fmaxf(r1 * (posb - 1.f), 0.f);
    const float d22 = fmaxf(r2 * (posb - 2.f), 0.f);
    const float d23 = fmaxf(r3 * (posb - 3.f), 0.f);
    const float a0 = fmaxf(__builtin_amdgcn_sqrtf(d20) * g2, CLIP2);
    const float a1 = fmaxf(__builtin_amdgcn_sqrtf(d21) * g2, CLIP2);
    const float a2 = fmaxf(__builtin_amdgcn_sqrtf(d22) * g2, CLIP2);
    const float a3 = fmaxf(__builtin_amdgcn_sqrtf(d23) * g2, CLIP2);
    const float p0 = exp2f(l[0] * exp2f(a0));
    const float p1 = exp2f(l[1] * exp2f(a1));
    const float p2 = exp2f(l[2] * exp2f(a2));
    const float p3 = exp2f(l[3] * exp2f(a3));
    z2 += (p0 + p1) + (p2 + p3);
    uint2 r; r.x = cvtpk_bf16(p0, p1); r.y = cvtpk_bf16(p2, p3);
    return r;
  };

  const int Cp = (count + 1) & ~1;
  for (int tl = 0; tl < Cp; tl += 2) {
    const int t0 = c0 + tl, t1 = t0 + 1;
    float la[4], lb[4];
    calc_l(t0, la);
    const bool v1 = (tl + 1 < count);    // wave-uniform
    if (v1) calc_l(t1, lb);
    // V loads are carry-independent: issue before the serial sm4 chain
    const int jb = t0 * 16;
    bf16x8 vf0 = *(const bf16x8*)(vbase + (size_t)l15 * 1024 + jb + hi * 8);
    bf16x8 vf1 = *(const bf16x8*)(vbase + (size_t)(16 + l15) * 1024 + jb + hi * 8);
    uint2 uA = sm4(la, t0 * 16 + hi * 4);
    uint2 uB = make_uint2(0u, 0u);
    if (v1) uB = sm4(lb, t1 * 16 + hi * 4);
    // regroup C-layout P^T (k=hi*4+r) into B-frag (k=hi*8..hi*8+7) over 32 k
    const int srcA = l15 + (((2 * hi) & 3) << 4);
    const int srcB = l15 + (((2 * hi + 1) & 3) << 4);
    unsigned a00 = (unsigned)__shfl((int)uA.x, srcA);
    unsigned a01 = (unsigned)__shfl((int)uB.x, srcA);
    unsigned a10 = (unsigned)__shfl((int)uA.y, srcA);
    unsigned a11 = (unsigned)__shfl((int)uB.y, srcA);
    unsigned b00 = (unsigned)__shfl((int)uA.x, srcB);
    unsigned b01 = (unsigned)__shfl((int)uB.x, srcB);
    unsigned b10 = (unsigned)__shfl((int)uA.y, srcB);
    unsigned b11 = (unsigned)__shfl((int)uB.y, srcB);
    const bool up = hi >= 2;
    union { unsigned u[4]; bf16x8 v; } pf;
    pf.u[0] = up ? a01 : a00;
    pf.u[1] = up ? a11 : a10;
    pf.u[2] = up ? b01 : b00;
    pf.u[3] = up ? b11 : b10;
    acc0 = __builtin_amdgcn_mfma_f32_16x16x32_bf16(vf0, pf.v, acc0, 0, 0, 0);
    acc1 = __builtin_amdgcn_mfma_f32_16x16x32_bf16(vf1, pf.v, acc1, 0, 0, 0);
  }

  z2 += __shfl_xor(z2, 16);
  z2 += __shfl_xor(z2, 32);
  if (lane < 16) z2buf[w][lane] = z2;
#pragma unroll
  for (int j = 0; j < 4; ++j) {
    accbuf[j][w][lane] = acc0[j];
    accbuf[4 + j][w][lane] = acc1[j];
  }
  __syncthreads();

  if (w == 0) {
    const float z2t = z2buf[0][l15] + z2buf[1][l15] + z2buf[2][l15] + z2buf[3][l15];
    const float inv2 = z2t > 0.f ? 1.f / z2t : 0.f;  // 0 => excl row 0 (zero_pad)
    u16* aop = ao + ((size_t)(b * 1024 + i)) * 256 + h * 32;
    float s0[4], s1[4];
#pragma unroll
    for (int j = 0; j < 4; ++j) {
      s0[j] = (accbuf[j][0][lane] + accbuf[j][1][lane] + accbuf[j][2][lane] + accbuf[j][3][lane]) * inv2;
      s1[j] = (accbuf[4 + j][0][lane] + accbuf[4 + j][1][lane] + accbuf[4 + j][2][lane] + accbuf[4 + j][3][lane]) * inv2;
    }
    uint2 o0, o1;
    o0.x = cvtpk_bf16(s0[0], s0[1]); o0.y = cvtpk_bf16(s0[2], s0[3]);
    o1.x = cvtpk_bf16(s1[0], s1[1]); o1.y = cvtpk_bf16(s1[2], s1[3]);
    *(uint2*)(aop + hi * 4) = o0;
    *(uint2*)(aop + 16 + hi * 4) = o1;
  }
}

// ---------------------------------------------------------------------------
// x = LN(res + add) * g + b ; add is bf16 (saves HBM traffic).
// ---------------------------------------------------------------------------
__global__ __launch_bounds__(256) void add_ln_kernel(
    const float* __restrict__ res, const u16* __restrict__ add,
    const float* __restrict__ g, const float* __restrict__ b,
    float* __restrict__ outf, u16* __restrict__ outb) {
  const int lane = threadIdx.x & 63, wid = threadIdx.x >> 6;
  const size_t row = (size_t)blockIdx.x * 4 + wid;
  const size_t base = row * 256 + lane * 4;
  float4 rv = *(const float4*)(res + base);
  u16x4 av = *(const u16x4*)(add + base);
  float x0 = rv.x + bf2f(av[0]), x1 = rv.y + bf2f(av[1]);
  float x2 = rv.z + bf2f(av[2]), x3 = rv.w + bf2f(av[3]);
  float sm = wred_sum(x0 + x1 + x2 + x3);
  float mu = sm * (1.f / 256.f);
  float d0 = x0 - mu, d1 = x1 - mu, d2 = x2 - mu, d3 = x3 - mu;
  float vs = wred_sum(d0 * d0 + d1 * d1 + d2 * d2 + d3 * d3);
  float rs = rsqrtf(vs * (1.f / 256.f) + 1e-5f);
  float4 gv = *(const float4*)(g + lane * 4);
  float4 bv = *(const float4*)(b + lane * 4);
  float o0 = d0 * rs * gv.x + bv.x;
  float o1 = d1 * rs * gv.y + bv.y;
  float o2 = d2 * rs * gv.z + bv.z;
  float o3 = d3 * rs * gv.w + bv.w;
  float4 ov = {o0, o1, o2, o3};
  *(float4*)(outf + base) = ov;
  u16x4 wv; wv[0] = f2bf(o0); wv[1] = f2bf(o1); wv[2] = f2bf(o2); wv[3] = f2bf(o3);
  *(u16x4*)(outb + base) = wv;
}

__global__ __launch_bounds__(256) void cast_bf_kernel(
    const float* __restrict__ in, u16* __restrict__ out) {
  size_t i = ((size_t)blockIdx.x * 256 + threadIdx.x) * 8;
  float4 a = *(const float4*)(in + i);
  float4 c = *(const float4*)(in + i + 4);
  u16x8 o;
  o[0] = f2bf(a.x); o[1] = f2bf(a.y); o[2] = f2bf(a.z); o[3] = f2bf(a.w);
  o[4] = f2bf(c.x); o[5] = f2bf(c.y); o[6] = f2bf(c.z); o[7] = f2bf(c.w);
  *(u16x8*)(out + i) = o;
}

// Wt[z*dstStride + n*K + k] = bf16(W[z*K*N + k*N + n])
__global__ __launch_bounds__(256) void transpose_cast_kernel(
    const float* __restrict__ W, u16* __restrict__ Wt, int K, int N,
    int dstStride) {
  __shared__ float t[32][33];
  const size_t lo = (size_t)blockIdx.z * K * N;
  const size_t lod = (size_t)blockIdx.z * dstStride;
  int n0 = blockIdx.x * 32, k0 = blockIdx.y * 32;
  int tx = threadIdx.x, ty = threadIdx.y;  // 32 x 8
#pragma unroll
  for (int r = 0; r < 32; r += 8)
    t[ty + r][tx] = W[lo + (size_t)(k0 + ty + r) * N + n0 + tx];
  __syncthreads();
#pragma unroll
  for (int r = 0; r < 32; r += 8)
    Wt[lod + (size_t)(n0 + ty + r) * K + k0 + tx] = f2bf(t[tx][ty + r]);
}

// ---------------------------------------------------------------------------
extern "C" void kernel_launch(void* const* d_in, const int* in_sizes, int n_in,
                              void* d_out, int out_size, void* d_ws,
                              size_t ws_size, hipStream_t stream) {
  const float* q_embed = (const float*)d_in[0];
  const float* qa_embed = (const float*)d_in[1];
  const float* Wk = (const float*)d_in[2];
  const float* bk = (const float*)d_in[3];
  const float* Wv = (const float*)d_in[4];
  const float* bv = (const float*)d_in[5];
  const float* Wo = (const float*)d_in[6];
  const float* bo = (const float*)d_in[7];
  const float* gammas = (const float*)d_in[8];
  const float* ln1_g = (const float*)d_in[9];
  const float* ln1_b = (const float*)d_in[10];
  const float* W1 = (const float*)d_in[11];
  const float* b1 = (const float*)d_in[12];
  const float* W2 = (const float*)d_in[13];
  const float* b2 = (const float*)d_in[14];
  const float* ln2_g = (const float*)d_in[15];
  const float* ln2_b = (const float*)d_in[16];

  const size_t ACT_F32 = (size_t)8192 * 256 * 4;  // 8 MB
  const size_t ACT_BF = (size_t)8192 * 256 * 2;   // 4 MB
  char* p = (char*)d_ws;
  auto carve = [&](size_t bytes) {
    void* r = (void*)p;
    p += (bytes + 255) & ~(size_t)255;
    return r;
  };
  float* yb = (float*)carve(ACT_F32);
  float* xb = (float*)carve(ACT_F32);
  u16* pofb = (u16*)carve(ACT_BF);
  u16* xbf = (u16*)carve(ACT_BF);
  u16* ybf = (u16*)carve(ACT_BF);
  u16* qkbf = (u16*)carve(ACT_BF);
  u16* vTb = (u16*)carve(ACT_BF);
  u16* aobf = (u16*)carve(ACT_BF);
  u16* hbf = (u16*)carve((size_t)8192 * 1024 * 2);  // 16 MB
  u16* Wkvt = (u16*)carve((size_t)3 * 131072 * 2);
  u16* Wot = (u16*)carve((size_t)3 * 65536 * 2);
  u16* W1t = (u16*)carve((size_t)3 * 262144 * 2);
  u16* W2t = (u16*)carve((size_t)3 * 262144 * 2);

  dim3 tb(32, 8);
  transpose_cast_kernel<<<dim3(8, 8, 3), tb, 0, stream>>>(Wk, Wkvt, 256, 256, 131072);
  transpose_cast_kernel<<<dim3(8, 8, 3), tb, 0, stream>>>(Wv, Wkvt + 65536, 256, 256, 131072);
  transpose_cast_kernel<<<dim3(8, 8, 3), tb, 0, stream>>>(Wo, Wot, 256, 256, 65536);
  transpose_cast_kernel<<<dim3(32, 8, 3), tb, 0, stream>>>(W1, W1t, 256, 1024, 262144);
  transpose_cast_kernel<<<dim3(8, 32, 3), tb, 0, stream>>>(W2, W2t, 1024, 256, 262144);
  cast_bf_kernel<<<1024, 256, 0, stream>>>(q_embed, xbf);
  cast_bf_kernel<<<1024, 256, 0, stream>>>(qa_embed, ybf);

  const dim3 gP(128, 4), gKV(128, 4), gW1(128, 8);
  const dim3 gA(64, 64);

  // ---- block 0: layer 0, y = qa, incl mask, FFN ----
  gemm_kv_kernel<<<gKV, 256, 0, stream>>>(ybf, Wkvt, bk, bv, qkbf, vTb, 8192, 512, 256);
  attn_mfma_kernel<<<gA, 256, 0, stream>>>(qkbf, vTb, aobf, gammas, 0);
  gemm_kernel<0, 0, 1, 0><<<gP, 256, 0, stream>>>(aobf, Wot, bo, nullptr, pofb, 8192, 256, 256);
  add_ln_kernel<<<2048, 256, 0, stream>>>(qa_embed, pofb, ln1_g, ln1_b, yb, ybf);
  gemm_w_kernel<1><<<gW1, 256, 0, stream>>>(ybf, W1t, b1, hbf, 8192, 1024, 256);
  gemm_kernel<0, 0, 1, 0><<<gP, 256, 0, stream>>>(hbf, W2t, b2, nullptr, pofb, 8192, 256, 1024);
  add_ln_kernel<<<2048, 256, 0, stream>>>(yb, pofb, ln2_g, ln2_b, yb, ybf);

  // ---- block 1: layer 1, x = q_embed, incl mask, no FFN ----
  gemm_kv_kernel<<<gKV, 256, 0, stream>>>(xbf, Wkvt + 131072, bk + 256, bv + 256, qkbf, vTb, 8192, 512, 256);
  attn_mfma_kernel<<<gA, 256, 0, stream>>>(qkbf, vTb, aobf, gammas + 8, 0);
  gemm_kernel<0, 0, 1, 0><<<gP, 256, 0, stream>>>(aobf, Wot + 65536, bo + 256, nullptr, pofb, 8192, 256, 256);
  add_ln_kernel<<<2048, 256, 0, stream>>>(q_embed, pofb, ln1_g + 256, ln1_b + 256, xb, xbf);

  // ---- block 2: layer 2, q/k from x, v from y, excl mask (zero_pad natural) ----
  // Fused KV writes V(x) into vTb (garbage), then the V(y) GEMM fully
  // overwrites vTb before attention reads it (same stream => ordered).
  gemm_kv_kernel<<<gKV, 256, 0, stream>>>(xbf, Wkvt + 262144, bk + 512, bv + 512, qkbf, vTb, 8192, 512, 256);
  gemm_kernel<0, 0, 0, 1><<<gP, 256, 0, stream>>>(ybf, Wkvt + 262144 + 65536, bv + 512, nullptr, vTb, 8192, 256, 256);
  attn_mfma_kernel<<<gA, 256, 0, stream>>>(qkbf, vTb, aobf, gammas + 16, 1);
  gemm_kernel<0, 0, 1, 0><<<gP, 256, 0, stream>>>(aobf, Wot + 131072, bo + 512, nullptr, pofb, 8192, 256, 256);
  add_ln_kernel<<<2048, 256, 0, stream>>>(xb, pofb, ln1_g + 512, ln1_b + 512, xb, xbf);
  gemm_w_kernel<1><<<gW1, 256, 0, stream>>>(xbf, W1t + 524288, b1 + 2048, hbf, 8192, 1024, 256);
  gemm_kernel<0, 0, 1, 0><<<gP, 256, 0, stream>>>(hbf, W2t + 524288, b2 + 512, nullptr, pofb, 8192, 256, 1024);
  add_ln_kernel<<<2048, 256, 0, stream>>>(xb, pofb, ln2_g + 512, ln2_b + 512, (float*)d_out, xbf);
}

// Round 12
// 307.524 us; speedup vs baseline: 1.1083x; 1.0202x over previous
//
#include <hip/hip_runtime.h>

typedef unsigned short u16;
typedef float f32x4 __attribute__((ext_vector_type(4)));
typedef __bf16 bf16x8 __attribute__((ext_vector_type(8)));
typedef u16 u16x8 __attribute__((ext_vector_type(8)));
typedef u16 u16x4 __attribute__((ext_vector_type(4)));

__device__ __forceinline__ u16 f2bf(float f) {
  union { float f; unsigned u; } v; v.f = f;
  unsigned r = (v.u + 0x7FFFu + ((v.u >> 16) & 1u)) >> 16;
  return (u16)r;
}
__device__ __forceinline__ unsigned cvtpk_bf16(float lo, float hi) {
  unsigned r;
  asm("v_cvt_pk_bf16_f32 %0, %1, %2" : "=v"(r) : "v"(lo), "v"(hi));
  return r;
}

// ---------------------------------------------------------------------------
// bf16 MFMA GEMM, 64x64 tile (used only for V(y) head-transposed scatter).
// ---------------------------------------------------------------------------
__global__ __launch_bounds__(256) void gemm_vt_kernel(
    const u16* __restrict__ A, const u16* __restrict__ Bt,
    const float* __restrict__ bias, u16* __restrict__ vT, int M, int N, int K) {
  __shared__ u16 As[64 * 64];
  __shared__ u16 Bs[64 * 64];
  const int tid = threadIdx.x;
  const int lane = tid & 63;
  const int w = tid >> 6;
  const int m0 = blockIdx.x * 64;
  const int n0 = blockIdx.y * 64;
  const int wr = (w >> 1) * 32;
  const int wc = (w & 1) * 32;
  const int l15 = lane & 15, hi = lane >> 4;

  f32x4 acc[2][2] = {};

  for (int k0 = 0; k0 < K; k0 += 64) {
#pragma unroll
    for (int rep = 0; rep < 2; ++rep) {
      int idx = tid + rep * 256;
      int row = idx >> 3, c8 = idx & 7;
      int cs = ((c8 ^ (row & 7)) << 3);
      __builtin_amdgcn_global_load_lds(
          (const __attribute__((address_space(1))) void*)(A + (size_t)(m0 + row) * K + k0 + cs),
          (__attribute__((address_space(3))) void*)(&As[idx * 8]), 16, 0, 0);
      __builtin_amdgcn_global_load_lds(
          (const __attribute__((address_space(1))) void*)(Bt + (size_t)(n0 + row) * K + k0 + cs),
          (__attribute__((address_space(3))) void*)(&Bs[idx * 8]), 16, 0, 0);
    }
    __syncthreads();
#pragma unroll
    for (int kk = 0; kk < 2; ++kk) {
      int kb = (kk * 32 + (hi << 3)) << 1;
      bf16x8 af[2], bfr[2];
#pragma unroll
      for (int mf = 0; mf < 2; ++mf) {
        int m = wr + mf * 16 + l15;
        af[mf] = *(const bf16x8*)((const char*)As + m * 128 + (kb ^ ((m & 7) << 4)));
      }
#pragma unroll
      for (int nf = 0; nf < 2; ++nf) {
        int n = wc + nf * 16 + l15;
        bfr[nf] = *(const bf16x8*)((const char*)Bs + n * 128 + (kb ^ ((n & 7) << 4)));
      }
#pragma unroll
      for (int mf = 0; mf < 2; ++mf)
#pragma unroll
        for (int nf = 0; nf < 2; ++nf)
          acc[mf][nf] = __builtin_amdgcn_mfma_f32_16x16x32_bf16(af[mf], bfr[nf], acc[mf][nf], 0, 0, 0);
    }
    __syncthreads();
  }

#pragma unroll
  for (int mf = 0; mf < 2; ++mf)
#pragma unroll
    for (int nf = 0; nf < 2; ++nf) {
      int col = n0 + wc + nf * 16 + l15;
      float bia = bias[col];
      u16x4 tv;
#pragma unroll
      for (int r = 0; r < 4; ++r) {
        float val = acc[mf][nf][r] + bia;
        tv[r] = f2bf(val);
      }
      int row0 = m0 + wr + mf * 16 + (hi << 2);
      size_t addr = (((size_t)(row0 >> 10) * 8 + (col >> 5)) * 32 + (col & 31)) * 1024 + (row0 & 1023);
      *(u16x4*)(vT + addr) = tv;
    }
}

// ---------------------------------------------------------------------------
// Wide bf16 MFMA GEMM, 64(M) x 128(N) tile, BK=64. bf16 row-major out, RELU.
// Used for W1 (N=1024).
// ---------------------------------------------------------------------------
template <int RELU>
__global__ __launch_bounds__(256) void gemm_w_kernel(
    const u16* __restrict__ A, const u16* __restrict__ Bt,
    const float* __restrict__ bias, u16* __restrict__ Cbf,
    int M, int N, int K) {
  __shared__ u16 As[64 * 64];
  __shared__ u16 Bs[128 * 64];
  const int tid = threadIdx.x;
  const int lane = tid & 63;
  const int w = tid >> 6;
  const int m0 = blockIdx.x * 64;
  const int n0 = blockIdx.y * 128;
  const int wr = (w >> 1) * 32;   // 0 or 32
  const int wc = (w & 1) * 64;    // 0 or 64
  const int l15 = lane & 15, hi = lane >> 4;

  f32x4 acc[2][4] = {};

  for (int k0 = 0; k0 < K; k0 += 64) {
#pragma unroll
    for (int rep = 0; rep < 2; ++rep) {
      int idx = tid + rep * 256;
      int row = idx >> 3, c8 = idx & 7;
      int cs = ((c8 ^ (row & 7)) << 3);
      __builtin_amdgcn_global_load_lds(
          (const __attribute__((address_space(1))) void*)(A + (size_t)(m0 + row) * K + k0 + cs),
          (__attribute__((address_space(3))) void*)(&As[idx * 8]), 16, 0, 0);
    }
#pragma unroll
    for (int rep = 0; rep < 4; ++rep) {
      int idx = tid + rep * 256;
      int row = idx >> 3, c8 = idx & 7;
      int cs = ((c8 ^ (row & 7)) << 3);
      __builtin_amdgcn_global_load_lds(
          (const __attribute__((address_space(1))) void*)(Bt + (size_t)(n0 + row) * K + k0 + cs),
          (__attribute__((address_space(3))) void*)(&Bs[idx * 8]), 16, 0, 0);
    }
    __syncthreads();
#pragma unroll
    for (int kk = 0; kk < 2; ++kk) {
      int kb = (kk * 32 + (hi << 3)) << 1;
      bf16x8 af[2], bfr[4];
#pragma unroll
      for (int mf = 0; mf < 2; ++mf) {
        int m = wr + mf * 16 + l15;
        af[mf] = *(const bf16x8*)((const char*)As + m * 128 + (kb ^ ((m & 7) << 4)));
      }
#pragma unroll
      for (int nf = 0; nf < 4; ++nf) {
        int n = wc + nf * 16 + l15;
        bfr[nf] = *(const bf16x8*)((const char*)Bs + n * 128 + (kb ^ ((n & 7) << 4)));
      }
#pragma unroll
      for (int mf = 0; mf < 2; ++mf)
#pragma unroll
        for (int nf = 0; nf < 4; ++nf)
          acc[mf][nf] = __builtin_amdgcn_mfma_f32_16x16x32_bf16(af[mf], bfr[nf], acc[mf][nf], 0, 0, 0);
    }
    __syncthreads();
  }

#pragma unroll
  for (int mf = 0; mf < 2; ++mf)
#pragma unroll
    for (int nf = 0; nf < 4; ++nf) {
      int col = n0 + wc + nf * 16 + l15;
      float bia = bias[col];
#pragma unroll
      for (int r = 0; r < 4; ++r) {
        int row = m0 + wr + mf * 16 + (hi << 2) + r;
        float val = acc[mf][nf][r] + bia;
        if (RELU) val = fmaxf(val, 0.f);
        Cbf[(size_t)row * N + col] = f2bf(val);
      }
    }
}

// ---------------------------------------------------------------------------
// Fused K+V projection, wide 64x128 tile: A[8192,256] @ WkvT[512,256]^T.
// Cols 0..255 -> qkbf; 256..511 -> vT scatter. Grid (M/64, 4).
// ---------------------------------------------------------------------------
__global__ __launch_bounds__(256) void gemm_kv_kernel(
    const u16* __restrict__ A, const u16* __restrict__ Bt,
    const float* __restrict__ biasK, const float* __restrict__ biasV,
    u16* __restrict__ qkbf, u16* __restrict__ vT, int M, int N, int K) {
  __shared__ u16 As[64 * 64];
  __shared__ u16 Bs[128 * 64];
  const int tid = threadIdx.x;
  const int lane = tid & 63;
  const int w = tid >> 6;
  const int m0 = blockIdx.x * 64;
  const int n0 = blockIdx.y * 128;
  const int wr = (w >> 1) * 32;
  const int wc = (w & 1) * 64;
  const int l15 = lane & 15, hi = lane >> 4;

  f32x4 acc[2][4] = {};

  for (int k0 = 0; k0 < K; k0 += 64) {
#pragma unroll
    for (int rep = 0; rep < 2; ++rep) {
      int idx = tid + rep * 256;
      int row = idx >> 3, c8 = idx & 7;
      int cs = ((c8 ^ (row & 7)) << 3);
      __builtin_amdgcn_global_load_lds(
          (const __attribute__((address_space(1))) void*)(A + (size_t)(m0 + row) * K + k0 + cs),
          (__attribute__((address_space(3))) void*)(&As[idx * 8]), 16, 0, 0);
    }
#pragma unroll
    for (int rep = 0; rep < 4; ++rep) {
      int idx = tid + rep * 256;
      int row = idx >> 3, c8 = idx & 7;
      int cs = ((c8 ^ (row & 7)) << 3);
      __builtin_amdgcn_global_load_lds(
          (const __attribute__((address_space(1))) void*)(Bt + (size_t)(n0 + row) * K + k0 + cs),
          (__attribute__((address_space(3))) void*)(&Bs[idx * 8]), 16, 0, 0);
    }
    __syncthreads();
#pragma unroll
    for (int kk = 0; kk < 2; ++kk) {
      int kb = (kk * 32 + (hi << 3)) << 1;
      bf16x8 af[2], bfr[4];
#pragma unroll
      for (int mf = 0; mf < 2; ++mf) {
        int m = wr + mf * 16 + l15;
        af[mf] = *(const bf16x8*)((const char*)As + m * 128 + (kb ^ ((m & 7) << 4)));
      }
#pragma unroll
      for (int nf = 0; nf < 4; ++nf) {
        int n = wc + nf * 16 + l15;
        bfr[nf] = *(const bf16x8*)((const char*)Bs + n * 128 + (kb ^ ((n & 7) << 4)));
      }
#pragma unroll
      for (int mf = 0; mf < 2; ++mf)
#pragma unroll
        for (int nf = 0; nf < 4; ++nf)
          acc[mf][nf] = __builtin_amdgcn_mfma_f32_16x16x32_bf16(af[mf], bfr[nf], acc[mf][nf], 0, 0, 0);
    }
    __syncthreads();
  }

#pragma unroll
  for (int mf = 0; mf < 2; ++mf)
#pragma unroll
    for (int nf = 0; nf < 4; ++nf) {
      int col = n0 + wc + nf * 16 + l15;
      const bool isV = (col >= 256);
      float bia = isV ? biasV[col - 256] : biasK[col];
      u16x4 tv;
#pragma unroll
      for (int r = 0; r < 4; ++r) {
        int row = m0 + wr + mf * 16 + (hi << 2) + r;
        float val = acc[mf][nf][r] + bia;
        if (!isV) qkbf[(size_t)row * 256 + col] = f2bf(val);
        tv[r] = f2bf(val);
      }
      if (isV) {
        int row0 = m0 + wr + mf * 16 + (hi << 2);
        int vc = col - 256;
        size_t addr = (((size_t)(row0 >> 10) * 8 + (vc >> 5)) * 32 + (vc & 31)) * 1024 + (row0 & 1023);
        *(u16x4*)(vT + addr) = tv;
      }
    }
}

// ---------------------------------------------------------------------------
// Fused GEMM + bias + residual + LayerNorm. Tile 32(M) x 256(N=full row).
// C = A[M,K] @ Bt[256,K]^T + bias;  x = C + res;  out = LN(x)*g + b.
// 4 waves: (rowgrp = w>>1) 16 rows, (colh = w&1) 128 cols. Grid M/32.
// Row-sum: in-lane over nf, shfl_xor over 16-lane col-slice, LDS cross-wave.
// Writes f32 (outf) and bf16 (outb).
// ---------------------------------------------------------------------------
__global__ __launch_bounds__(256) void gemm_ln_kernel(
    const u16* __restrict__ A, const u16* __restrict__ Bt,
    const float* __restrict__ bias, const float* __restrict__ res,
    const float* __restrict__ g, const float* __restrict__ b,
    float* __restrict__ outf, u16* __restrict__ outb, int K) {
  __shared__ u16 As[32 * 64];    // 4 KB
  __shared__ u16 Bs[256 * 64];   // 32 KB
  __shared__ float red[2][32][2];

  const int tid = threadIdx.x;
  const int lane = tid & 63;
  const int w = tid >> 6;
  const int rowgrp = w >> 1, colh = w & 1;
  const int m0 = blockIdx.x * 32;
  const int l15 = lane & 15, hi = lane >> 4;

  f32x4 acc[8] = {};

  for (int k0 = 0; k0 < K; k0 += 64) {
    {
      int row = tid >> 3, c8 = tid & 7;
      int cs = ((c8 ^ (row & 7)) << 3);
      __builtin_amdgcn_global_load_lds(
          (const __attribute__((address_space(1))) void*)(A + (size_t)(m0 + row) * K + k0 + cs),
          (__attribute__((address_space(3))) void*)(&As[tid * 8]), 16, 0, 0);
    }
#pragma unroll
    for (int rep = 0; rep < 8; ++rep) {
      int idx = tid + rep * 256;
      int row = idx >> 3, c8 = idx & 7;
      int cs = ((c8 ^ (row & 7)) << 3);
      __builtin_amdgcn_global_load_lds(
          (const __attribute__((address_space(1))) void*)(Bt + (size_t)row * K + k0 + cs),
          (__attribute__((address_space(3))) void*)(&Bs[idx * 8]), 16, 0, 0);
    }
    __syncthreads();
#pragma unroll
    for (int kk = 0; kk < 2; ++kk) {
      int kb = (kk * 32 + (hi << 3)) << 1;
      int m = rowgrp * 16 + l15;
      bf16x8 af = *(const bf16x8*)((const char*)As + m * 128 + (kb ^ ((m & 7) << 4)));
      bf16x8 bfr[8];
#pragma unroll
      for (int nf = 0; nf < 8; ++nf) {
        int n = colh * 128 + nf * 16 + l15;
        bfr[nf] = *(const bf16x8*)((const char*)Bs + n * 128 + (kb ^ ((n & 7) << 4)));
      }
#pragma unroll
      for (int nf = 0; nf < 8; ++nf)
        acc[nf] = __builtin_amdgcn_mfma_f32_16x16x32_bf16(af, bfr[nf], acc[nf], 0, 0, 0);
    }
    __syncthreads();
  }

  // ---- epilogue: bias + residual, then LN over the 256-col rows ----
  const int rbase = m0 + rowgrp * 16 + hi * 4;
  float s[4] = {0.f, 0.f, 0.f, 0.f}, ss[4] = {0.f, 0.f, 0.f, 0.f};
#pragma unroll
  for (int nf = 0; nf < 8; ++nf) {
    int col = colh * 128 + nf * 16 + l15;
    float bia = bias[col];
#pragma unroll
    for (int r = 0; r < 4; ++r) {
      float v = acc[nf][r] + bia + res[(size_t)(rbase + r) * 256 + col];
      acc[nf][r] = v;
      s[r] += v;
      ss[r] += v * v;
    }
  }
#pragma unroll
  for (int r = 0; r < 4; ++r) {
#pragma unroll
    for (int o = 1; o < 16; o <<= 1) {
      s[r] += __shfl_xor(s[r], o);
      ss[r] += __shfl_xor(ss[r], o);
    }
  }
  if (l15 == 0) {
#pragma unroll
    for (int r = 0; r < 4; ++r) {
      red[colh][rowgrp * 16 + hi * 4 + r][0] = s[r];
      red[colh][rowgrp * 16 + hi * 4 + r][1] = ss[r];
    }
  }
  __syncthreads();
  float mu[4], rs[4];
#pragma unroll
  for (int r = 0; r < 4; ++r) {
    int rr = rowgrp * 16 + hi * 4 + r;
    float S = red[0][rr][0] + red[1][rr][0];
    float SS = red[0][rr][1] + red[1][rr][1];
    mu[r] = S * (1.f / 256.f);
    float var = SS * (1.f / 256.f) - mu[r] * mu[r];
    rs[r] = rsqrtf(var + 1e-5f);
  }
#pragma unroll
  for (int nf = 0; nf < 8; ++nf) {
    int col = colh * 128 + nf * 16 + l15;
    float gv = g[col], bv = b[col];
#pragma unroll
    for (int r = 0; r < 4; ++r) {
      float o = (acc[nf][r] - mu[r]) * rs[r] * gv + bv;
      size_t addr = (size_t)(rbase + r) * 256 + col;
      outf[addr] = o;
      outb[addr] = f2bf(o);
    }
  }
}

// ---------------------------------------------------------------------------
// MFMA distance-decay attention (R10/R11 structure, validated).
// ---------------------------------------------------------------------------
__global__ __launch_bounds__(256) void attn_mfma_kernel(
    const u16* __restrict__ qkbf, const u16* __restrict__ vT,
    u16* __restrict__ ao, const float* __restrict__ gam, int excl) {
  __shared__ float zbuf[4][16];
  __shared__ float z2buf[4][16];
  __shared__ float accbuf[8][4][64];

  const int lane = threadIdx.x & 63, w = threadIdx.x >> 6;
  const int qt = 63 - blockIdx.y;  // big-work blocks dispatch first
  const int bh = blockIdx.x;
  const int b = bh >> 3, h = bh & 7;
  const int q0 = qt * 16;
  const int l15 = lane & 15, hi = lane >> 4;
  const int i = q0 + l15;
  const float LOG2E = 1.4426950408889634f;
  const float g2 = -log1pf(__expf(gam[h])) * LOG2E;
  const float cscale = 0.17677669529663687f * LOG2E;
  const float CLIP2 = -16.609640474436812f;

  const u16* kbase = qkbf + (size_t)b * 1024 * 256 + h * 32;
  const u16* vbase = vT + (size_t)bh * 32 * 1024;
  const bf16x8 qfrag = *(const bf16x8*)(kbase + (size_t)i * 256 + hi * 8);

  const int mylim = i - excl;
  const int jmax = q0 + 15 - excl;
  const int ntiles = (jmax >> 4) + 1;
  const int C = (ntiles + 3) >> 2;
  const int c0 = w * C;
  const int tEnd = (c0 + C < ntiles) ? (c0 + C) : ntiles;
  const int count = (tEnd > c0) ? (tEnd - c0) : 0;

  auto calc_l = [&](int t, float* l) {
    bf16x8 kf = *(const bf16x8*)(kbase + (size_t)(t * 16 + l15) * 256 + hi * 8);
    f32x4 sA = {};
    sA = __builtin_amdgcn_mfma_f32_16x16x32_bf16(kf, qfrag, sA, 0, 0, 0);
    l[0] = sA[0] * cscale; l[1] = sA[1] * cscale;
    l[2] = sA[2] * cscale; l[3] = sA[3] * cscale;
    if (t == ntiles - 1) {
      const int kb = t * 16 + hi * 4;
      l[0] = (kb + 0 <= mylim) ? l[0] : -1000.f;
      l[1] = (kb + 1 <= mylim) ? l[1] : -1000.f;
      l[2] = (kb + 2 <= mylim) ? l[2] : -1000.f;
      l[3] = (kb + 3 <= mylim) ? l[3] : -1000.f;
    }
  };

  float zacc = 0.f;
  for (int t = c0; t < tEnd; ++t) {
    float l[4]; calc_l(t, l);
    zacc += (exp2f(l[0]) + exp2f(l[1])) + (exp2f(l[2]) + exp2f(l[3]));
  }
  zacc += __shfl_xor(zacc, 16);
  zacc += __shfl_xor(zacc, 32);
  if (lane < 16) zbuf[w][lane] = zacc;
  __syncthreads();

  const float zc0 = zbuf[0][l15], zc1 = zbuf[1][l15];
  const float zc2 = zbuf[2][l15], zc3 = zbuf[3][l15];
  const float Z = zc0 + zc1 + zc2 + zc3;
  const float invZ = Z > 0.f ? 1.f / Z : 0.f;
  float prefix = 0.f;
  if (w > 0) prefix += zc0;
  if (w > 1) prefix += zc1;
  if (w > 2) prefix += zc2;

  float carry = prefix, z2 = 0.f;
  f32x4 acc0 = {}, acc1 = {};

  auto sm4 = [&](const float* l, int kb) -> uint2 {
    const float e0 = exp2f(l[0]), e1 = exp2f(l[1]);
    const float e2 = exp2f(l[2]), e3 = exp2f(l[3]);
    const float cA = e0 + e1, cB2 = cA + e2, cC = cB2 + e3;
    float vsc = cC;
    float tmp = __shfl_up(vsc, 16); if (hi >= 1) vsc += tmp;
    tmp = __shfl_up(vsc, 32); if (hi >= 2) vsc += tmp;
    const float exg = vsc - cC;
    const float tot = __shfl(vsc, l15 + 48);
    const float cb = carry + exg;
    carry += tot;
    const float posb = (float)(i - kb);
    const float r0 = (Z - (cb + e0)) * invZ;
    const float r1 = (Z - (cb + cA)) * invZ;
    const float r2 = (Z - (cb + cB2)) * invZ;
    const float r3 = (Z - (cb + cC)) * invZ;
    const float d20 = fmaxf(r0 * posb, 0.f);
    const float d21 = fmaxf(r1 * (posb - 1.f), 0.f);
    const float d22 = fmaxf(r2 * (posb - 2.f), 0.f);
    const float d23 = fmaxf(r3 * (posb - 3.f), 0.f);
    const float a0 = fmaxf(__builtin_amdgcn_sqrtf(d20) * g2, CLIP2);
    const float a1 = fmaxf(__builtin_amdgcn_sqrtf(d21) * g2, CLIP2);
    const float a2 = fmaxf(__builtin_amdgcn_sqrtf(d22) * g2, CLIP2);
    const float a3 = fmaxf(__builtin_amdgcn_sqrtf(d23) * g2, CLIP2);
    const float p0 = exp2f(l[0] * exp2f(a0));
    const float p1 = exp2f(l[1] * exp2f(a1));
    const float p2 = exp2f(l[2] * exp2f(a2));
    const float p3 = exp2f(l[3] * exp2f(a3));
    z2 += (p0 + p1) + (p2 + p3);
    uint2 r; r.x = cvtpk_bf16(p0, p1); r.y = cvtpk_bf16(p2, p3);
    return r;
  };

  const int Cp = (count + 1) & ~1;
  for (int tl = 0; tl < Cp; tl += 2) {
    const int t0 = c0 + tl, t1 = t0 + 1;
    float la[4], lb[4];
    calc_l(t0, la);
    const bool v1 = (tl + 1 < count);
    if (v1) calc_l(t1, lb);
    const int jb = t0 * 16;
    bf16x8 vf0 = *(const bf16x8*)(vbase + (size_t)l15 * 1024 + jb + hi * 8);
    bf16x8 vf1 = *(const bf16x8*)(vbase + (size_t)(16 + l15) * 1024 + jb + hi * 8);
    uint2 uA = sm4(la, t0 * 16 + hi * 4);
    uint2 uB = make_uint2(0u, 0u);
    if (v1) uB = sm4(lb, t1 * 16 + hi * 4);
    const int srcA = l15 + (((2 * hi) & 3) << 4);
    const int srcB = l15 + (((2 * hi + 1) & 3) << 4);
    unsigned a00 = (unsigned)__shfl((int)uA.x, srcA);
    unsigned a01 = (unsigned)__shfl((int)uB.x, srcA);
    unsigned a10 = (unsigned)__shfl((int)uA.y, srcA);
    unsigned a11 = (unsigned)__shfl((int)uB.y, srcA);
    unsigned b00 = (unsigned)__shfl((int)uA.x, srcB);
    unsigned b01 = (unsigned)__shfl((int)uB.x, srcB);
    unsigned b10 = (unsigned)__shfl((int)uA.y, srcB);
    unsigned b11 = (unsigned)__shfl((int)uB.y, srcB);
    const bool up = hi >= 2;
    union { unsigned u[4]; bf16x8 v; } pf;
    pf.u[0] = up ? a01 : a00;
    pf.u[1] = up ? a11 : a10;
    pf.u[2] = up ? b01 : b00;
    pf.u[3] = up ? b11 : b10;
    acc0 = __builtin_amdgcn_mfma_f32_16x16x32_bf16(vf0, pf.v, acc0, 0, 0, 0);
    acc1 = __builtin_amdgcn_mfma_f32_16x16x32_bf16(vf1, pf.v, acc1, 0, 0, 0);
  }

  z2 += __shfl_xor(z2, 16);
  z2 += __shfl_xor(z2, 32);
  if (lane < 16) z2buf[w][lane] = z2;
#pragma unroll
  for (int j = 0; j < 4; ++j) {
    accbuf[j][w][lane] = acc0[j];
    accbuf[4 + j][w][lane] = acc1[j];
  }
  __syncthreads();

  if (w == 0) {
    const float z2t = z2buf[0][l15] + z2buf[1][l15] + z2buf[2][l15] + z2buf[3][l15];
    const float inv2 = z2t > 0.f ? 1.f / z2t : 0.f;
    u16* aop = ao + ((size_t)(b * 1024 + i)) * 256 + h * 32;
    float s0[4], s1[4];
#pragma unroll
    for (int j = 0; j < 4; ++j) {
      s0[j] = (accbuf[j][0][lane] + accbuf[j][1][lane] + accbuf[j][2][lane] + accbuf[j][3][lane]) * inv2;
      s1[j] = (accbuf[4 + j][0][lane] + accbuf[4 + j][1][lane] + accbuf[4 + j][2][lane] + accbuf[4 + j][3][lane]) * inv2;
    }
    uint2 o0, o1;
    o0.x = cvtpk_bf16(s0[0], s0[1]); o0.y = cvtpk_bf16(s0[2], s0[3]);
    o1.x = cvtpk_bf16(s1[0], s1[1]); o1.y = cvtpk_bf16(s1[2], s1[3]);
    *(uint2*)(aop + hi * 4) = o0;
    *(uint2*)(aop + 16 + hi * 4) = o1;
  }
}

// ---------------------------------------------------------------------------
// One-shot prep: all 5 weight transposes (f32 -> bf16, [K][N] -> [N][K]) and
// both input casts, dispatched by flat blockIdx. Block = (32, 8).
// ---------------------------------------------------------------------------
__global__ __launch_bounds__(256) void prep_kernel(
    const float* __restrict__ Wk, const float* __restrict__ Wv,
    const float* __restrict__ Wo, const float* __restrict__ W1,
    const float* __restrict__ W2, const float* __restrict__ qe,
    const float* __restrict__ qae, u16* __restrict__ Wkvt,
    u16* __restrict__ Wot, u16* __restrict__ W1t, u16* __restrict__ W2t,
    u16* __restrict__ xbf, u16* __restrict__ ybf) {
  __shared__ float t[32][33];
  const int bid = blockIdx.x;
  const int tx = threadIdx.x, ty = threadIdx.y;

  if (bid < 2112) {
    const float* src; u16* dst;
    int K, N, n0, k0;
    size_t so, doff;
    if (bid < 576) {
      int wsel = bid / 192, r = bid % 192, z = r >> 6, tt = r & 63;
      K = 256; N = 256;
      n0 = (tt & 7) * 32; k0 = (tt >> 3) * 32;
      so = (size_t)z * 65536;
      if (wsel == 0)      { src = Wk; dst = Wkvt;        doff = (size_t)z * 131072; }
      else if (wsel == 1) { src = Wv; dst = Wkvt + 65536; doff = (size_t)z * 131072; }
      else                { src = Wo; dst = Wot;          doff = (size_t)z * 65536; }
    } else if (bid < 1344) {
      int r = bid - 576, z = r >> 8, tt = r & 255;
      K = 256; N = 1024;
      n0 = (tt & 31) * 32; k0 = (tt >> 5) * 32;
      src = W1; dst = W1t;
      so = (size_t)z * 262144; doff = (size_t)z * 262144;
    } else {
      int r = bid - 1344, z = r >> 8, tt = r & 255;
      K = 1024; N = 256;
      n0 = (tt & 7) * 32; k0 = (tt >> 3) * 32;
      src = W2; dst = W2t;
      so = (size_t)z * 262144; doff = (size_t)z * 262144;
    }
#pragma unroll
    for (int r = 0; r < 32; r += 8)
      t[ty + r][tx] = src[so + (size_t)(k0 + ty + r) * N + n0 + tx];
    __syncthreads();
#pragma unroll
    for (int r = 0; r < 32; r += 8)
      dst[doff + (size_t)(n0 + ty + r) * K + k0 + tx] = f2bf(t[tx][ty + r]);
  } else {
    int r = bid - 2112;  // 0..2047
    const float* in = (r < 1024) ? qe : qae;
    u16* out = (r < 1024) ? xbf : ybf;
    int rr = r & 1023;
    int tid = ty * 32 + tx;
    size_t i = ((size_t)rr * 256 + tid) * 8;
    float4 a = *(const float4*)(in + i);
    float4 c = *(const float4*)(in + i + 4);
    u16x8 o;
    o[0] = f2bf(a.x); o[1] = f2bf(a.y); o[2] = f2bf(a.z); o[3] = f2bf(a.w);
    o[4] = f2bf(c.x); o[5] = f2bf(c.y); o[6] = f2bf(c.z); o[7] = f2bf(c.w);
    *(u16x8*)(out + i) = o;
  }
}

// ---------------------------------------------------------------------------
extern "C" void kernel_launch(void* const* d_in, const int* in_sizes, int n_in,
                              void* d_out, int out_size, void* d_ws,
                              size_t ws_size, hipStream_t stream) {
  const float* q_embed = (const float*)d_in[0];
  const float* qa_embed = (const float*)d_in[1];
  const float* Wk = (const float*)d_in[2];
  const float* bk = (const float*)d_in[3];
  const float* Wv = (const float*)d_in[4];
  const float* bv = (const float*)d_in[5];
  const float* Wo = (const float*)d_in[6];
  const float* bo = (const float*)d_in[7];
  const float* gammas = (const float*)d_in[8];
  const float* ln1_g = (const float*)d_in[9];
  const float* ln1_b = (const float*)d_in[10];
  const float* W1 = (const float*)d_in[11];
  const float* b1 = (const float*)d_in[12];
  const float* W2 = (const float*)d_in[13];
  const float* b2 = (const float*)d_in[14];
  const float* ln2_g = (const float*)d_in[15];
  const float* ln2_b = (const float*)d_in[16];

  const size_t ACT_F32 = (size_t)8192 * 256 * 4;  // 8 MB
  const size_t ACT_BF = (size_t)8192 * 256 * 2;   // 4 MB
  char* p = (char*)d_ws;
  auto carve = [&](size_t bytes) {
    void* r = (void*)p;
    p += (bytes + 255) & ~(size_t)255;
    return r;
  };
  float* yb = (float*)carve(ACT_F32);
  float* xb = (float*)carve(ACT_F32);
  u16* xbf = (u16*)carve(ACT_BF);
  u16* ybf = (u16*)carve(ACT_BF);
  u16* qkbf = (u16*)carve(ACT_BF);
  u16* vTb = (u16*)carve(ACT_BF);
  u16* aobf = (u16*)carve(ACT_BF);
  u16* hbf = (u16*)carve((size_t)8192 * 1024 * 2);  // 16 MB
  u16* Wkvt = (u16*)carve((size_t)3 * 131072 * 2);
  u16* Wot = (u16*)carve((size_t)3 * 65536 * 2);
  u16* W1t = (u16*)carve((size_t)3 * 262144 * 2);
  u16* W2t = (u16*)carve((size_t)3 * 262144 * 2);

  prep_kernel<<<4160, dim3(32, 8), 0, stream>>>(
      Wk, Wv, Wo, W1, W2, q_embed, qa_embed, Wkvt, Wot, W1t, W2t, xbf, ybf);

  const dim3 gKV(128, 4), gW1(128, 8), gVT(128, 4);
  const dim3 gA(64, 64);

  // ---- block 0: layer 0, y = qa, incl mask, FFN ----
  gemm_kv_kernel<<<gKV, 256, 0, stream>>>(ybf, Wkvt, bk, bv, qkbf, vTb, 8192, 512, 256);
  attn_mfma_kernel<<<gA, 256, 0, stream>>>(qkbf, vTb, aobf, gammas, 0);
  gemm_ln_kernel<<<256, 256, 0, stream>>>(aobf, Wot, bo, qa_embed, ln1_g, ln1_b, yb, ybf, 256);
  gemm_w_kernel<1><<<gW1, 256, 0, stream>>>(ybf, W1t, b1, hbf, 8192, 1024, 256);
  gemm_ln_kernel<<<256, 256, 0, stream>>>(hbf, W2t, b2, yb, ln2_g, ln2_b, yb, ybf, 1024);

  // ---- block 1: layer 1, x = q_embed, incl mask, no FFN ----
  gemm_kv_kernel<<<gKV, 256, 0, stream>>>(xbf, Wkvt + 131072, bk + 256, bv + 256, qkbf, vTb, 8192, 512, 256);
  attn_mfma_kernel<<<gA, 256, 0, stream>>>(qkbf, vTb, aobf, gammas + 8, 0);
  gemm_ln_kernel<<<256, 256, 0, stream>>>(aobf, Wot + 65536, bo + 256, q_embed, ln1_g + 256, ln1_b + 256, xb, xbf, 256);

  // ---- block 2: layer 2, q/k from x, v from y, excl mask (zero_pad natural) ----
  // Fused KV writes V(x) into vTb (garbage), then the V(y) GEMM fully
  // overwrites vTb before attention reads it (same stream => ordered).
  gemm_kv_kernel<<<gKV, 256, 0, stream>>>(xbf, Wkvt + 262144, bk + 512, bv + 512, qkbf, vTb, 8192, 512, 256);
  gemm_vt_kernel<<<gVT, 256, 0, stream>>>(ybf, Wkvt + 262144 + 65536, bv + 512, vTb, 8192, 256, 256);
  attn_mfma_kernel<<<gA, 256, 0, stream>>>(qkbf, vTb, aobf, gammas + 16, 1);
  gemm_ln_kernel<<<256, 256, 0, stream>>>(aobf, Wot + 131072, bo + 512, xb, ln1_g + 512, ln1_b + 512, xb, xbf, 256);
  gemm_w_kernel<1><<<gW1, 256, 0, stream>>>(xbf, W1t + 524288, b1 + 2048, hbf, 8192, 1024, 256);
  gemm_ln_kernel<<<256, 256, 0, stream>>>(hbf, W2t + 524288, b2 + 512, xb, ln2_g + 512, ln2_b + 512, (float*)d_out, xbf, 1024);
}

// Round 13
// 290.461 us; speedup vs baseline: 1.1734x; 1.0587x over previous
//
#include <hip/hip_runtime.h>

typedef unsigned short u16;
typedef float f32x4 __attribute__((ext_vector_type(4)));
typedef __bf16 bf16x8 __attribute__((ext_vector_type(8)));
typedef u16 u16x8 __attribute__((ext_vector_type(8)));
typedef u16 u16x4 __attribute__((ext_vector_type(4)));

#define LAYER_STRIDE 2097152  // 8192*256 elements (one activation slab)

__device__ __forceinline__ u16 f2bf(float f) {
  union { float f; unsigned u; } v; v.f = f;
  unsigned r = (v.u + 0x7FFFu + ((v.u >> 16) & 1u)) >> 16;
  return (u16)r;
}
__device__ __forceinline__ unsigned cvtpk_bf16(float lo, float hi) {
  unsigned r;
  asm("v_cvt_pk_bf16_f32 %0, %1, %2" : "=v"(r) : "v"(lo), "v"(hi));
  return r;
}

// ---------------------------------------------------------------------------
// bf16 MFMA GEMM, 64x64 tile (used only for V(y) head-transposed scatter).
// ---------------------------------------------------------------------------
__global__ __launch_bounds__(256) void gemm_vt_kernel(
    const u16* __restrict__ A, const u16* __restrict__ Bt,
    const float* __restrict__ bias, u16* __restrict__ vT, int M, int N, int K) {
  __shared__ u16 As[64 * 64];
  __shared__ u16 Bs[64 * 64];
  const int tid = threadIdx.x;
  const int lane = tid & 63;
  const int w = tid >> 6;
  const int m0 = blockIdx.x * 64;
  const int n0 = blockIdx.y * 64;
  const int wr = (w >> 1) * 32;
  const int wc = (w & 1) * 32;
  const int l15 = lane & 15, hi = lane >> 4;

  f32x4 acc[2][2] = {};

  for (int k0 = 0; k0 < K; k0 += 64) {
#pragma unroll
    for (int rep = 0; rep < 2; ++rep) {
      int idx = tid + rep * 256;
      int row = idx >> 3, c8 = idx & 7;
      int cs = ((c8 ^ (row & 7)) << 3);
      __builtin_amdgcn_global_load_lds(
          (const __attribute__((address_space(1))) void*)(A + (size_t)(m0 + row) * K + k0 + cs),
          (__attribute__((address_space(3))) void*)(&As[idx * 8]), 16, 0, 0);
      __builtin_amdgcn_global_load_lds(
          (const __attribute__((address_space(1))) void*)(Bt + (size_t)(n0 + row) * K + k0 + cs),
          (__attribute__((address_space(3))) void*)(&Bs[idx * 8]), 16, 0, 0);
    }
    __syncthreads();
#pragma unroll
    for (int kk = 0; kk < 2; ++kk) {
      int kb = (kk * 32 + (hi << 3)) << 1;
      bf16x8 af[2], bfr[2];
#pragma unroll
      for (int mf = 0; mf < 2; ++mf) {
        int m = wr + mf * 16 + l15;
        af[mf] = *(const bf16x8*)((const char*)As + m * 128 + (kb ^ ((m & 7) << 4)));
      }
#pragma unroll
      for (int nf = 0; nf < 2; ++nf) {
        int n = wc + nf * 16 + l15;
        bfr[nf] = *(const bf16x8*)((const char*)Bs + n * 128 + (kb ^ ((n & 7) << 4)));
      }
#pragma unroll
      for (int mf = 0; mf < 2; ++mf)
#pragma unroll
        for (int nf = 0; nf < 2; ++nf)
          acc[mf][nf] = __builtin_amdgcn_mfma_f32_16x16x32_bf16(af[mf], bfr[nf], acc[mf][nf], 0, 0, 0);
    }
    __syncthreads();
  }

#pragma unroll
  for (int mf = 0; mf < 2; ++mf)
#pragma unroll
    for (int nf = 0; nf < 2; ++nf) {
      int col = n0 + wc + nf * 16 + l15;
      float bia = bias[col];
      u16x4 tv;
#pragma unroll
      for (int r = 0; r < 4; ++r) {
        float val = acc[mf][nf][r] + bia;
        tv[r] = f2bf(val);
      }
      int row0 = m0 + wr + mf * 16 + (hi << 2);
      size_t addr = (((size_t)(row0 >> 10) * 8 + (col >> 5)) * 32 + (col & 31)) * 1024 + (row0 & 1023);
      *(u16x4*)(vT + addr) = tv;
    }
}

// ---------------------------------------------------------------------------
// Wide bf16 MFMA GEMM, 64(M) x 128(N) tile, BK=64. bf16 row-major out, RELU.
// ---------------------------------------------------------------------------
template <int RELU>
__global__ __launch_bounds__(256) void gemm_w_kernel(
    const u16* __restrict__ A, const u16* __restrict__ Bt,
    const float* __restrict__ bias, u16* __restrict__ Cbf,
    int M, int N, int K) {
  __shared__ u16 As[64 * 64];
  __shared__ u16 Bs[128 * 64];
  const int tid = threadIdx.x;
  const int lane = tid & 63;
  const int w = tid >> 6;
  const int m0 = blockIdx.x * 64;
  const int n0 = blockIdx.y * 128;
  const int wr = (w >> 1) * 32;   // 0 or 32
  const int wc = (w & 1) * 64;    // 0 or 64
  const int l15 = lane & 15, hi = lane >> 4;

  f32x4 acc[2][4] = {};

  for (int k0 = 0; k0 < K; k0 += 64) {
#pragma unroll
    for (int rep = 0; rep < 2; ++rep) {
      int idx = tid + rep * 256;
      int row = idx >> 3, c8 = idx & 7;
      int cs = ((c8 ^ (row & 7)) << 3);
      __builtin_amdgcn_global_load_lds(
          (const __attribute__((address_space(1))) void*)(A + (size_t)(m0 + row) * K + k0 + cs),
          (__attribute__((address_space(3))) void*)(&As[idx * 8]), 16, 0, 0);
    }
#pragma unroll
    for (int rep = 0; rep < 4; ++rep) {
      int idx = tid + rep * 256;
      int row = idx >> 3, c8 = idx & 7;
      int cs = ((c8 ^ (row & 7)) << 3);
      __builtin_amdgcn_global_load_lds(
          (const __attribute__((address_space(1))) void*)(Bt + (size_t)(n0 + row) * K + k0 + cs),
          (__attribute__((address_space(3))) void*)(&Bs[idx * 8]), 16, 0, 0);
    }
    __syncthreads();
#pragma unroll
    for (int kk = 0; kk < 2; ++kk) {
      int kb = (kk * 32 + (hi << 3)) << 1;
      bf16x8 af[2], bfr[4];
#pragma unroll
      for (int mf = 0; mf < 2; ++mf) {
        int m = wr + mf * 16 + l15;
        af[mf] = *(const bf16x8*)((const char*)As + m * 128 + (kb ^ ((m & 7) << 4)));
      }
#pragma unroll
      for (int nf = 0; nf < 4; ++nf) {
        int n = wc + nf * 16 + l15;
        bfr[nf] = *(const bf16x8*)((const char*)Bs + n * 128 + (kb ^ ((n & 7) << 4)));
      }
#pragma unroll
      for (int mf = 0; mf < 2; ++mf)
#pragma unroll
        for (int nf = 0; nf < 4; ++nf)
          acc[mf][nf] = __builtin_amdgcn_mfma_f32_16x16x32_bf16(af[mf], bfr[nf], acc[mf][nf], 0, 0, 0);
    }
    __syncthreads();
  }

#pragma unroll
  for (int mf = 0; mf < 2; ++mf)
#pragma unroll
    for (int nf = 0; nf < 4; ++nf) {
      int col = n0 + wc + nf * 16 + l15;
      float bia = bias[col];
#pragma unroll
      for (int r = 0; r < 4; ++r) {
        int row = m0 + wr + mf * 16 + (hi << 2) + r;
        float val = acc[mf][nf][r] + bia;
        if (RELU) val = fmaxf(val, 0.f);
        Cbf[(size_t)row * N + col] = f2bf(val);
      }
    }
}

// ---------------------------------------------------------------------------
// Fused K+V projection, wide 64x128 tile, z-merged over layers.
// z = blockIdx.z: A = (z ? A1 : A0), weights/biases/outputs offset by z.
// Cols 0..255 -> qk2 slab z; 256..511 -> vT2 slab z (scatter).
// ---------------------------------------------------------------------------
__global__ __launch_bounds__(256) void gemm_kv_kernel(
    const u16* __restrict__ A0, const u16* __restrict__ A1,
    const u16* __restrict__ WkvtBase, const float* __restrict__ bkBase,
    const float* __restrict__ bvBase, u16* __restrict__ qk2,
    u16* __restrict__ vT2) {
  __shared__ u16 As[64 * 64];
  __shared__ u16 Bs[128 * 64];
  const int z = blockIdx.z;
  const u16* A = z ? A1 : A0;
  const u16* Bt = WkvtBase + (size_t)z * 131072;
  const float* biasK = bkBase + z * 256;
  const float* biasV = bvBase + z * 256;
  u16* qkbf = qk2 + (size_t)z * LAYER_STRIDE;
  u16* vT = vT2 + (size_t)z * LAYER_STRIDE;
  const int K = 256;

  const int tid = threadIdx.x;
  const int lane = tid & 63;
  const int w = tid >> 6;
  const int m0 = blockIdx.x * 64;
  const int n0 = blockIdx.y * 128;
  const int wr = (w >> 1) * 32;
  const int wc = (w & 1) * 64;
  const int l15 = lane & 15, hi = lane >> 4;

  f32x4 acc[2][4] = {};

  for (int k0 = 0; k0 < K; k0 += 64) {
#pragma unroll
    for (int rep = 0; rep < 2; ++rep) {
      int idx = tid + rep * 256;
      int row = idx >> 3, c8 = idx & 7;
      int cs = ((c8 ^ (row & 7)) << 3);
      __builtin_amdgcn_global_load_lds(
          (const __attribute__((address_space(1))) void*)(A + (size_t)(m0 + row) * K + k0 + cs),
          (__attribute__((address_space(3))) void*)(&As[idx * 8]), 16, 0, 0);
    }
#pragma unroll
    for (int rep = 0; rep < 4; ++rep) {
      int idx = tid + rep * 256;
      int row = idx >> 3, c8 = idx & 7;
      int cs = ((c8 ^ (row & 7)) << 3);
      __builtin_amdgcn_global_load_lds(
          (const __attribute__((address_space(1))) void*)(Bt + (size_t)(n0 + row) * K + k0 + cs),
          (__attribute__((address_space(3))) void*)(&Bs[idx * 8]), 16, 0, 0);
    }
    __syncthreads();
#pragma unroll
    for (int kk = 0; kk < 2; ++kk) {
      int kb = (kk * 32 + (hi << 3)) << 1;
      bf16x8 af[2], bfr[4];
#pragma unroll
      for (int mf = 0; mf < 2; ++mf) {
        int m = wr + mf * 16 + l15;
        af[mf] = *(const bf16x8*)((const char*)As + m * 128 + (kb ^ ((m & 7) << 4)));
      }
#pragma unroll
      for (int nf = 0; nf < 4; ++nf) {
        int n = wc + nf * 16 + l15;
        bfr[nf] = *(const bf16x8*)((const char*)Bs + n * 128 + (kb ^ ((n & 7) << 4)));
      }
#pragma unroll
      for (int mf = 0; mf < 2; ++mf)
#pragma unroll
        for (int nf = 0; nf < 4; ++nf)
          acc[mf][nf] = __builtin_amdgcn_mfma_f32_16x16x32_bf16(af[mf], bfr[nf], acc[mf][nf], 0, 0, 0);
    }
    __syncthreads();
  }

#pragma unroll
  for (int mf = 0; mf < 2; ++mf)
#pragma unroll
    for (int nf = 0; nf < 4; ++nf) {
      int col = n0 + wc + nf * 16 + l15;
      const bool isV = (col >= 256);
      float bia = isV ? biasV[col - 256] : biasK[col];
      u16x4 tv;
#pragma unroll
      for (int r = 0; r < 4; ++r) {
        int row = m0 + wr + mf * 16 + (hi << 2) + r;
        float val = acc[mf][nf][r] + bia;
        if (!isV) qkbf[(size_t)row * 256 + col] = f2bf(val);
        tv[r] = f2bf(val);
      }
      if (isV) {
        int row0 = m0 + wr + mf * 16 + (hi << 2);
        int vc = col - 256;
        size_t addr = (((size_t)(row0 >> 10) * 8 + (vc >> 5)) * 32 + (vc & 31)) * 1024 + (row0 & 1023);
        *(u16x4*)(vT + addr) = tv;
      }
    }
}

// ---------------------------------------------------------------------------
// Fused GEMM + bias + residual + LayerNorm. Tile 32(M) x 256(N=full row).
// z = blockIdx.y selects layer slab (A/Bt/bias/g/b strided; res/out pairs).
// ---------------------------------------------------------------------------
__global__ __launch_bounds__(256) void gemm_ln_kernel(
    const u16* __restrict__ Abase, const u16* __restrict__ BtBase,
    const float* __restrict__ biasBase, const float* __restrict__ res0,
    const float* __restrict__ res1, const float* __restrict__ gBase,
    const float* __restrict__ bBase, float* __restrict__ outf0,
    float* __restrict__ outf1, u16* __restrict__ outb0,
    u16* __restrict__ outb1, int K) {
  __shared__ u16 As[32 * 64];    // 4 KB
  __shared__ u16 Bs[256 * 64];   // 32 KB
  __shared__ float red[2][32][2];

  const int z = blockIdx.y;
  const u16* A = Abase + (size_t)z * LAYER_STRIDE;
  const u16* Bt = BtBase + (size_t)z * 65536;
  const float* bias = biasBase + z * 256;
  const float* res = z ? res1 : res0;
  const float* g = gBase + z * 256;
  const float* b = bBase + z * 256;
  float* outf = z ? outf1 : outf0;
  u16* outb = z ? outb1 : outb0;

  const int tid = threadIdx.x;
  const int lane = tid & 63;
  const int w = tid >> 6;
  const int rowgrp = w >> 1, colh = w & 1;
  const int m0 = blockIdx.x * 32;
  const int l15 = lane & 15, hi = lane >> 4;

  f32x4 acc[8] = {};

  for (int k0 = 0; k0 < K; k0 += 64) {
    {
      int row = tid >> 3, c8 = tid & 7;
      int cs = ((c8 ^ (row & 7)) << 3);
      __builtin_amdgcn_global_load_lds(
          (const __attribute__((address_space(1))) void*)(A + (size_t)(m0 + row) * K + k0 + cs),
          (__attribute__((address_space(3))) void*)(&As[tid * 8]), 16, 0, 0);
    }
#pragma unroll
    for (int rep = 0; rep < 8; ++rep) {
      int idx = tid + rep * 256;
      int row = idx >> 3, c8 = idx & 7;
      int cs = ((c8 ^ (row & 7)) << 3);
      __builtin_amdgcn_global_load_lds(
          (const __attribute__((address_space(1))) void*)(Bt + (size_t)row * K + k0 + cs),
          (__attribute__((address_space(3))) void*)(&Bs[idx * 8]), 16, 0, 0);
    }
    __syncthreads();
#pragma unroll
    for (int kk = 0; kk < 2; ++kk) {
      int kb = (kk * 32 + (hi << 3)) << 1;
      int m = rowgrp * 16 + l15;
      bf16x8 af = *(const bf16x8*)((const char*)As + m * 128 + (kb ^ ((m & 7) << 4)));
      bf16x8 bfr[8];
#pragma unroll
      for (int nf = 0; nf < 8; ++nf) {
        int n = colh * 128 + nf * 16 + l15;
        bfr[nf] = *(const bf16x8*)((const char*)Bs + n * 128 + (kb ^ ((n & 7) << 4)));
      }
#pragma unroll
      for (int nf = 0; nf < 8; ++nf)
        acc[nf] = __builtin_amdgcn_mfma_f32_16x16x32_bf16(af, bfr[nf], acc[nf], 0, 0, 0);
    }
    __syncthreads();
  }

  // ---- epilogue: bias + residual, then LN over the 256-col rows ----
  const int rbase = m0 + rowgrp * 16 + hi * 4;
  float s[4] = {0.f, 0.f, 0.f, 0.f}, ss[4] = {0.f, 0.f, 0.f, 0.f};
#pragma unroll
  for (int nf = 0; nf < 8; ++nf) {
    int col = colh * 128 + nf * 16 + l15;
    float bia = bias[col];
#pragma unroll
    for (int r = 0; r < 4; ++r) {
      float v = acc[nf][r] + bia + res[(size_t)(rbase + r) * 256 + col];
      acc[nf][r] = v;
      s[r] += v;
      ss[r] += v * v;
    }
  }
#pragma unroll
  for (int r = 0; r < 4; ++r) {
#pragma unroll
    for (int o = 1; o < 16; o <<= 1) {
      s[r] += __shfl_xor(s[r], o);
      ss[r] += __shfl_xor(ss[r], o);
    }
  }
  if (l15 == 0) {
#pragma unroll
    for (int r = 0; r < 4; ++r) {
      red[colh][rowgrp * 16 + hi * 4 + r][0] = s[r];
      red[colh][rowgrp * 16 + hi * 4 + r][1] = ss[r];
    }
  }
  __syncthreads();
  float mu[4], rs[4];
#pragma unroll
  for (int r = 0; r < 4; ++r) {
    int rr = rowgrp * 16 + hi * 4 + r;
    float S = red[0][rr][0] + red[1][rr][0];
    float SS = red[0][rr][1] + red[1][rr][1];
    mu[r] = S * (1.f / 256.f);
    float var = SS * (1.f / 256.f) - mu[r] * mu[r];
    rs[r] = rsqrtf(var + 1e-5f);
  }
#pragma unroll
  for (int nf = 0; nf < 8; ++nf) {
    int col = colh * 128 + nf * 16 + l15;
    float gv = g[col], bv = b[col];
#pragma unroll
    for (int r = 0; r < 4; ++r) {
      float o = (acc[nf][r] - mu[r]) * rs[r] * gv + bv;
      size_t addr = (size_t)(rbase + r) * 256 + col;
      outf[addr] = o;
      outb[addr] = f2bf(o);
    }
  }
}

// ---------------------------------------------------------------------------
// MFMA distance-decay attention (validated structure), z-merged over layers.
// z = blockIdx.z: qk/vT/ao slabs and gamma offset by z.
// ---------------------------------------------------------------------------
__global__ __launch_bounds__(256) void attn_mfma_kernel(
    const u16* __restrict__ qk2, const u16* __restrict__ vT2,
    u16* __restrict__ ao2, const float* __restrict__ gamBase, int excl) {
  __shared__ float zbuf[4][16];
  __shared__ float z2buf[4][16];
  __shared__ float accbuf[8][4][64];

  const int z = blockIdx.z;
  const u16* qkbf = qk2 + (size_t)z * LAYER_STRIDE;
  const u16* vT = vT2 + (size_t)z * LAYER_STRIDE;
  u16* ao = ao2 + (size_t)z * LAYER_STRIDE;
  const float* gam = gamBase + z * 8;

  const int lane = threadIdx.x & 63, w = threadIdx.x >> 6;
  const int qt = 63 - blockIdx.y;  // big-work blocks dispatch first
  const int bh = blockIdx.x;
  const int b = bh >> 3, h = bh & 7;
  const int q0 = qt * 16;
  const int l15 = lane & 15, hi = lane >> 4;
  const int i = q0 + l15;
  const float LOG2E = 1.4426950408889634f;
  const float g2 = -log1pf(__expf(gam[h])) * LOG2E;
  const float cscale = 0.17677669529663687f * LOG2E;
  const float CLIP2 = -16.609640474436812f;

  const u16* kbase = qkbf + (size_t)b * 1024 * 256 + h * 32;
  const u16* vbase = vT + (size_t)bh * 32 * 1024;
  const bf16x8 qfrag = *(const bf16x8*)(kbase + (size_t)i * 256 + hi * 8);

  const int mylim = i - excl;
  const int jmax = q0 + 15 - excl;
  const int ntiles = (jmax >> 4) + 1;
  const int C = (ntiles + 3) >> 2;
  const int c0 = w * C;
  const int tEnd = (c0 + C < ntiles) ? (c0 + C) : ntiles;
  const int count = (tEnd > c0) ? (tEnd - c0) : 0;

  auto calc_l = [&](int t, float* l) {
    bf16x8 kf = *(const bf16x8*)(kbase + (size_t)(t * 16 + l15) * 256 + hi * 8);
    f32x4 sA = {};
    sA = __builtin_amdgcn_mfma_f32_16x16x32_bf16(kf, qfrag, sA, 0, 0, 0);
    l[0] = sA[0] * cscale; l[1] = sA[1] * cscale;
    l[2] = sA[2] * cscale; l[3] = sA[3] * cscale;
    if (t == ntiles - 1) {
      const int kb = t * 16 + hi * 4;
      l[0] = (kb + 0 <= mylim) ? l[0] : -1000.f;
      l[1] = (kb + 1 <= mylim) ? l[1] : -1000.f;
      l[2] = (kb + 2 <= mylim) ? l[2] : -1000.f;
      l[3] = (kb + 3 <= mylim) ? l[3] : -1000.f;
    }
  };

  float zacc = 0.f;
  for (int t = c0; t < tEnd; ++t) {
    float l[4]; calc_l(t, l);
    zacc += (exp2f(l[0]) + exp2f(l[1])) + (exp2f(l[2]) + exp2f(l[3]));
  }
  zacc += __shfl_xor(zacc, 16);
  zacc += __shfl_xor(zacc, 32);
  if (lane < 16) zbuf[w][lane] = zacc;
  __syncthreads();

  const float zc0 = zbuf[0][l15], zc1 = zbuf[1][l15];
  const float zc2 = zbuf[2][l15], zc3 = zbuf[3][l15];
  const float Z = zc0 + zc1 + zc2 + zc3;
  const float invZ = Z > 0.f ? 1.f / Z : 0.f;
  float prefix = 0.f;
  if (w > 0) prefix += zc0;
  if (w > 1) prefix += zc1;
  if (w > 2) prefix += zc2;

  float carry = prefix, z2 = 0.f;
  f32x4 acc0 = {}, acc1 = {};

  auto sm4 = [&](const float* l, int kb) -> uint2 {
    const float e0 = exp2f(l[0]), e1 = exp2f(l[1]);
    const float e2 = exp2f(l[2]), e3 = exp2f(l[3]);
    const float cA = e0 + e1, cB2 = cA + e2, cC = cB2 + e3;
    float vsc = cC;
    float tmp = __shfl_up(vsc, 16); if (hi >= 1) vsc += tmp;
    tmp = __shfl_up(vsc, 32); if (hi >= 2) vsc += tmp;
    const float exg = vsc - cC;
    const float tot = __shfl(vsc, l15 + 48);
    const float cb = carry + exg;
    carry += tot;
    const float posb = (float)(i - kb);
    const float r0 = (Z - (cb + e0)) * invZ;
    const float r1 = (Z - (cb + cA)) * invZ;
    const float r2 = (Z - (cb + cB2)) * invZ;
    const float r3 = (Z - (cb + cC)) * invZ;
    const float d20 = fmaxf(r0 * posb, 0.f);
    const float d21 = fmaxf(r1 * (posb - 1.f), 0.f);
    const float d22 = fmaxf(r2 * (posb - 2.f), 0.f);
    const float d23 = fmaxf(r3 * (posb - 3.f), 0.f);
    const float a0 = fmaxf(__builtin_amdgcn_sqrtf(d20) * g2, CLIP2);
    const float a1 = fmaxf(__builtin_amdgcn_sqrtf(d21) * g2, CLIP2);
    const float a2 = fmaxf(__builtin_amdgcn_sqrtf(d22) * g2, CLIP2);
    const float a3 = fmaxf(__builtin_amdgcn_sqrtf(d23) * g2, CLIP2);
    const float p0 = exp2f(l[0] * exp2f(a0));
    const float p1 = exp2f(l[1] * exp2f(a1));
    const float p2 = exp2f(l[2] * exp2f(a2));
    const float p3 = exp2f(l[3] * exp2f(a3));
    z2 += (p0 + p1) + (p2 + p3);
    uint2 r; r.x = cvtpk_bf16(p0, p1); r.y = cvtpk_bf16(p2, p3);
    return r;
  };

  const int Cp = (count + 1) & ~1;
  for (int tl = 0; tl < Cp; tl += 2) {
    const int t0 = c0 + tl, t1 = t0 + 1;
    float la[4], lb[4];
    calc_l(t0, la);
    const bool v1 = (tl + 1 < count);
    if (v1) calc_l(t1, lb);
    const int jb = t0 * 16;
    bf16x8 vf0 = *(const bf16x8*)(vbase + (size_t)l15 * 1024 + jb + hi * 8);
    bf16x8 vf1 = *(const bf16x8*)(vbase + (size_t)(16 + l15) * 1024 + jb + hi * 8);
    uint2 uA = sm4(la, t0 * 16 + hi * 4);
    uint2 uB = make_uint2(0u, 0u);
    if (v1) uB = sm4(lb, t1 * 16 + hi * 4);
    const int srcA = l15 + (((2 * hi) & 3) << 4);
    const int srcB = l15 + (((2 * hi + 1) & 3) << 4);
    unsigned a00 = (unsigned)__shfl((int)uA.x, srcA);
    unsigned a01 = (unsigned)__shfl((int)uB.x, srcA);
    unsigned a10 = (unsigned)__shfl((int)uA.y, srcA);
    unsigned a11 = (unsigned)__shfl((int)uB.y, srcA);
    unsigned b00 = (unsigned)__shfl((int)uA.x, srcB);
    unsigned b01 = (unsigned)__shfl((int)uB.x, srcB);
    unsigned b10 = (unsigned)__shfl((int)uA.y, srcB);
    unsigned b11 = (unsigned)__shfl((int)uB.y, srcB);
    const bool up = hi >= 2;
    union { unsigned u[4]; bf16x8 v; } pf;
    pf.u[0] = up ? a01 : a00;
    pf.u[1] = up ? a11 : a10;
    pf.u[2] = up ? b01 : b00;
    pf.u[3] = up ? b11 : b10;
    acc0 = __builtin_amdgcn_mfma_f32_16x16x32_bf16(vf0, pf.v, acc0, 0, 0, 0);
    acc1 = __builtin_amdgcn_mfma_f32_16x16x32_bf16(vf1, pf.v, acc1, 0, 0, 0);
  }

  z2 += __shfl_xor(z2, 16);
  z2 += __shfl_xor(z2, 32);
  if (lane < 16) z2buf[w][lane] = z2;
#pragma unroll
  for (int j = 0; j < 4; ++j) {
    accbuf[j][w][lane] = acc0[j];
    accbuf[4 + j][w][lane] = acc1[j];
  }
  __syncthreads();

  if (w == 0) {
    const float z2t = z2buf[0][l15] + z2buf[1][l15] + z2buf[2][l15] + z2buf[3][l15];
    const float inv2 = z2t > 0.f ? 1.f / z2t : 0.f;
    u16* aop = ao + ((size_t)(b * 1024 + i)) * 256 + h * 32;
    float s0[4], s1[4];
#pragma unroll
    for (int j = 0; j < 4; ++j) {
      s0[j] = (accbuf[j][0][lane] + accbuf[j][1][lane] + accbuf[j][2][lane] + accbuf[j][3][lane]) * inv2;
      s1[j] = (accbuf[4 + j][0][lane] + accbuf[4 + j][1][lane] + accbuf[4 + j][2][lane] + accbuf[4 + j][3][lane]) * inv2;
    }
    uint2 o0, o1;
    o0.x = cvtpk_bf16(s0[0], s0[1]); o0.y = cvtpk_bf16(s0[2], s0[3]);
    o1.x = cvtpk_bf16(s1[0], s1[1]); o1.y = cvtpk_bf16(s1[2], s1[3]);
    *(uint2*)(aop + hi * 4) = o0;
    *(uint2*)(aop + 16 + hi * 4) = o1;
  }
}

// ---------------------------------------------------------------------------
// One-shot prep: all 5 weight transposes + both input casts.
// ---------------------------------------------------------------------------
__global__ __launch_bounds__(256) void prep_kernel(
    const float* __restrict__ Wk, const float* __restrict__ Wv,
    const float* __restrict__ Wo, const float* __restrict__ W1,
    const float* __restrict__ W2, const float* __restrict__ qe,
    const float* __restrict__ qae, u16* __restrict__ Wkvt,
    u16* __restrict__ Wot, u16* __restrict__ W1t, u16* __restrict__ W2t,
    u16* __restrict__ xbf, u16* __restrict__ ybf) {
  __shared__ float t[32][33];
  const int bid = blockIdx.x;
  const int tx = threadIdx.x, ty = threadIdx.y;

  if (bid < 2112) {
    const float* src; u16* dst;
    int K, N, n0, k0;
    size_t so, doff;
    if (bid < 576) {
      int wsel = bid / 192, r = bid % 192, z = r >> 6, tt = r & 63;
      K = 256; N = 256;
      n0 = (tt & 7) * 32; k0 = (tt >> 3) * 32;
      so = (size_t)z * 65536;
      if (wsel == 0)      { src = Wk; dst = Wkvt;        doff = (size_t)z * 131072; }
      else if (wsel == 1) { src = Wv; dst = Wkvt + 65536; doff = (size_t)z * 131072; }
      else                { src = Wo; dst = Wot;          doff = (size_t)z * 65536; }
    } else if (bid < 1344) {
      int r = bid - 576, z = r >> 8, tt = r & 255;
      K = 256; N = 1024;
      n0 = (tt & 31) * 32; k0 = (tt >> 5) * 32;
      src = W1; dst = W1t;
      so = (size_t)z * 262144; doff = (size_t)z * 262144;
    } else {
      int r = bid - 1344, z = r >> 8, tt = r & 255;
      K = 1024; N = 256;
      n0 = (tt & 7) * 32; k0 = (tt >> 3) * 32;
      src = W2; dst = W2t;
      so = (size_t)z * 262144; doff = (size_t)z * 262144;
    }
#pragma unroll
    for (int r = 0; r < 32; r += 8)
      t[ty + r][tx] = src[so + (size_t)(k0 + ty + r) * N + n0 + tx];
    __syncthreads();
#pragma unroll
    for (int r = 0; r < 32; r += 8)
      dst[doff + (size_t)(n0 + ty + r) * K + k0 + tx] = f2bf(t[tx][ty + r]);
  } else {
    int r = bid - 2112;  // 0..2047
    const float* in = (r < 1024) ? qe : qae;
    u16* out = (r < 1024) ? xbf : ybf;
    int rr = r & 1023;
    int tid = ty * 32 + tx;
    size_t i = ((size_t)rr * 256 + tid) * 8;
    float4 a = *(const float4*)(in + i);
    float4 c = *(const float4*)(in + i + 4);
    u16x8 o;
    o[0] = f2bf(a.x); o[1] = f2bf(a.y); o[2] = f2bf(a.z); o[3] = f2bf(a.w);
    o[4] = f2bf(c.x); o[5] = f2bf(c.y); o[6] = f2bf(c.z); o[7] = f2bf(c.w);
    *(u16x8*)(out + i) = o;
  }
}

// ---------------------------------------------------------------------------
extern "C" void kernel_launch(void* const* d_in, const int* in_sizes, int n_in,
                              void* d_out, int out_size, void* d_ws,
                              size_t ws_size, hipStream_t stream) {
  const float* q_embed = (const float*)d_in[0];
  const float* qa_embed = (const float*)d_in[1];
  const float* Wk = (const float*)d_in[2];
  const float* bk = (const float*)d_in[3];
  const float* Wv = (const float*)d_in[4];
  const float* bv = (const float*)d_in[5];
  const float* Wo = (const float*)d_in[6];
  const float* bo = (const float*)d_in[7];
  const float* gammas = (const float*)d_in[8];
  const float* ln1_g = (const float*)d_in[9];
  const float* ln1_b = (const float*)d_in[10];
  const float* W1 = (const float*)d_in[11];
  const float* b1 = (const float*)d_in[12];
  const float* W2 = (const float*)d_in[13];
  const float* b2 = (const float*)d_in[14];
  const float* ln2_g = (const float*)d_in[15];
  const float* ln2_b = (const float*)d_in[16];

  const size_t ACT_F32 = (size_t)8192 * 256 * 4;  // 8 MB
  const size_t ACT_BF = (size_t)8192 * 256 * 2;   // 4 MB
  char* p = (char*)d_ws;
  auto carve = [&](size_t bytes) {
    void* r = (void*)p;
    p += (bytes + 255) & ~(size_t)255;
    return r;
  };
  float* yb = (float*)carve(ACT_F32);
  float* xb = (float*)carve(ACT_F32);
  u16* xbf = (u16*)carve(ACT_BF);
  u16* ybf = (u16*)carve(ACT_BF);
  u16* qk2 = (u16*)carve(2 * ACT_BF);
  u16* vT2 = (u16*)carve(2 * ACT_BF);
  u16* ao2 = (u16*)carve(2 * ACT_BF);
  u16* hbf = (u16*)carve((size_t)8192 * 1024 * 2);  // 16 MB
  u16* Wkvt = (u16*)carve((size_t)3 * 131072 * 2);
  u16* Wot = (u16*)carve((size_t)3 * 65536 * 2);
  u16* W1t = (u16*)carve((size_t)3 * 262144 * 2);
  u16* W2t = (u16*)carve((size_t)3 * 262144 * 2);

  prep_kernel<<<4160, dim3(32, 8), 0, stream>>>(
      Wk, Wv, Wo, W1, W2, q_embed, qa_embed, Wkvt, Wot, W1t, W2t, xbf, ybf);

  // ---- layers 0 (y-chain) + 1 (x-chain) merged: independent until block 2 ----
  gemm_kv_kernel<<<dim3(128, 4, 2), 256, 0, stream>>>(ybf, xbf, Wkvt, bk, bv, qk2, vT2);
  attn_mfma_kernel<<<dim3(64, 64, 2), 256, 0, stream>>>(qk2, vT2, ao2, gammas, 0);
  gemm_ln_kernel<<<dim3(256, 2), 256, 0, stream>>>(
      ao2, Wot, bo, qa_embed, q_embed, ln1_g, ln1_b, yb, xb, ybf, xbf, 256);
  // block 0 FFN tail
  gemm_w_kernel<1><<<dim3(128, 8), 256, 0, stream>>>(ybf, W1t, b1, hbf, 8192, 1024, 256);
  gemm_ln_kernel<<<dim3(256, 1), 256, 0, stream>>>(
      hbf, W2t, b2, yb, yb, ln2_g, ln2_b, yb, yb, ybf, ybf, 1024);

  // ---- block 2: q/k from x, v from y, excl mask (zero_pad natural) ----
  // KV writes V(x) into vT2 slab 0 (garbage), then V(y) GEMM overwrites it.
  gemm_kv_kernel<<<dim3(128, 4, 1), 256, 0, stream>>>(xbf, xbf, Wkvt + 262144, bk + 512, bv + 512, qk2, vT2);
  gemm_vt_kernel<<<dim3(128, 4), 256, 0, stream>>>(ybf, Wkvt + 262144 + 65536, bv + 512, vT2, 8192, 256, 256);
  attn_mfma_kernel<<<dim3(64, 64, 1), 256, 0, stream>>>(qk2, vT2, ao2, gammas + 16, 1);
  gemm_ln_kernel<<<dim3(256, 1), 256, 0, stream>>>(
      ao2, Wot + 131072, bo + 512, xb, xb, ln1_g + 512, ln1_b + 512, xb, xb, xbf, xbf, 256);
  gemm_w_kernel<1><<<dim3(128, 8), 256, 0, stream>>>(xbf, W1t + 524288, b1 + 2048, hbf, 8192, 1024, 256);
  gemm_ln_kernel<<<dim3(256, 1), 256, 0, stream>>>(
      hbf, W2t + 524288, b2 + 512, xb, xb, ln2_g + 512, ln2_b + 512, (float*)d_out, (float*)d_out, xbf, xbf, 1024);
}

// Round 14
// 284.270 us; speedup vs baseline: 1.1990x; 1.0218x over previous
//
#include <hip/hip_runtime.h>

typedef unsigned short u16;
typedef float f32x4 __attribute__((ext_vector_type(4)));
typedef __bf16 bf16x8 __attribute__((ext_vector_type(8)));
typedef u16 u16x8 __attribute__((ext_vector_type(8)));
typedef u16 u16x4 __attribute__((ext_vector_type(4)));

#define LAYER_STRIDE 2097152  // 8192*256 elements (one activation slab)

__device__ __forceinline__ u16 f2bf(float f) {
  union { float f; unsigned u; } v; v.f = f;
  unsigned r = (v.u + 0x7FFFu + ((v.u >> 16) & 1u)) >> 16;
  return (u16)r;
}
__device__ __forceinline__ unsigned cvtpk_bf16(float lo, float hi) {
  unsigned r;
  asm("v_cvt_pk_bf16_f32 %0, %1, %2" : "=v"(r) : "v"(lo), "v"(hi));
  return r;
}

// ---------------------------------------------------------------------------
// Wide bf16 MFMA GEMM, 64(M) x 128(N) tile, BK=64. bf16 row-major out, RELU.
// ---------------------------------------------------------------------------
template <int RELU>
__global__ __launch_bounds__(256) void gemm_w_kernel(
    const u16* __restrict__ A, const u16* __restrict__ Bt,
    const float* __restrict__ bias, u16* __restrict__ Cbf,
    int M, int N, int K) {
  __shared__ u16 As[64 * 64];
  __shared__ u16 Bs[128 * 64];
  const int tid = threadIdx.x;
  const int lane = tid & 63;
  const int w = tid >> 6;
  const int m0 = blockIdx.x * 64;
  const int n0 = blockIdx.y * 128;
  const int wr = (w >> 1) * 32;   // 0 or 32
  const int wc = (w & 1) * 64;    // 0 or 64
  const int l15 = lane & 15, hi = lane >> 4;

  f32x4 acc[2][4] = {};

  for (int k0 = 0; k0 < K; k0 += 64) {
#pragma unroll
    for (int rep = 0; rep < 2; ++rep) {
      int idx = tid + rep * 256;
      int row = idx >> 3, c8 = idx & 7;
      int cs = ((c8 ^ (row & 7)) << 3);
      __builtin_amdgcn_global_load_lds(
          (const __attribute__((address_space(1))) void*)(A + (size_t)(m0 + row) * K + k0 + cs),
          (__attribute__((address_space(3))) void*)(&As[idx * 8]), 16, 0, 0);
    }
#pragma unroll
    for (int rep = 0; rep < 4; ++rep) {
      int idx = tid + rep * 256;
      int row = idx >> 3, c8 = idx & 7;
      int cs = ((c8 ^ (row & 7)) << 3);
      __builtin_amdgcn_global_load_lds(
          (const __attribute__((address_space(1))) void*)(Bt + (size_t)(n0 + row) * K + k0 + cs),
          (__attribute__((address_space(3))) void*)(&Bs[idx * 8]), 16, 0, 0);
    }
    __syncthreads();
#pragma unroll
    for (int kk = 0; kk < 2; ++kk) {
      int kb = (kk * 32 + (hi << 3)) << 1;
      bf16x8 af[2], bfr[4];
#pragma unroll
      for (int mf = 0; mf < 2; ++mf) {
        int m = wr + mf * 16 + l15;
        af[mf] = *(const bf16x8*)((const char*)As + m * 128 + (kb ^ ((m & 7) << 4)));
      }
#pragma unroll
      for (int nf = 0; nf < 4; ++nf) {
        int n = wc + nf * 16 + l15;
        bfr[nf] = *(const bf16x8*)((const char*)Bs + n * 128 + (kb ^ ((n & 7) << 4)));
      }
#pragma unroll
      for (int mf = 0; mf < 2; ++mf)
#pragma unroll
        for (int nf = 0; nf < 4; ++nf)
          acc[mf][nf] = __builtin_amdgcn_mfma_f32_16x16x32_bf16(af[mf], bfr[nf], acc[mf][nf], 0, 0, 0);
    }
    __syncthreads();
  }

#pragma unroll
  for (int mf = 0; mf < 2; ++mf)
#pragma unroll
    for (int nf = 0; nf < 4; ++nf) {
      int col = n0 + wc + nf * 16 + l15;
      float bia = bias[col];
#pragma unroll
      for (int r = 0; r < 4; ++r) {
        int row = m0 + wr + mf * 16 + (hi << 2) + r;
        float val = acc[mf][nf][r] + bia;
        if (RELU) val = fmaxf(val, 0.f);
        Cbf[(size_t)row * N + col] = f2bf(val);
      }
    }
}

// ---------------------------------------------------------------------------
// Fused K+V projection, wide 64x128 tile, z-merged over layers, with
// per-column-half A selection: K-half (cols 0..255) reads Ak, V-half
// (cols 256..511) reads Av (block-uniform: each block's slab is one half).
// Layers 0/1: Ak==Av. Block 2: Ak=x, Av=y (removes separate V(y) GEMM).
// Cols 0..255 -> qk2 slab z; 256..511 -> vT2 slab z (scatter).
// ---------------------------------------------------------------------------
__global__ __launch_bounds__(256) void gemm_kv_kernel(
    const u16* __restrict__ Ak0, const u16* __restrict__ Av0,
    const u16* __restrict__ Ak1, const u16* __restrict__ Av1,
    const u16* __restrict__ WkvtBase, const float* __restrict__ bkBase,
    const float* __restrict__ bvBase, u16* __restrict__ qk2,
    u16* __restrict__ vT2) {
  __shared__ u16 As[64 * 64];
  __shared__ u16 Bs[128 * 64];
  const int z = blockIdx.z;
  const int n0 = blockIdx.y * 128;
  const bool vhalf = (n0 >= 256);
  const u16* A = z ? (vhalf ? Av1 : Ak1) : (vhalf ? Av0 : Ak0);
  const u16* Bt = WkvtBase + (size_t)z * 131072;
  const float* biasK = bkBase + z * 256;
  const float* biasV = bvBase + z * 256;
  u16* qkbf = qk2 + (size_t)z * LAYER_STRIDE;
  u16* vT = vT2 + (size_t)z * LAYER_STRIDE;
  const int K = 256;

  const int tid = threadIdx.x;
  const int lane = tid & 63;
  const int w = tid >> 6;
  const int m0 = blockIdx.x * 64;
  const int wr = (w >> 1) * 32;
  const int wc = (w & 1) * 64;
  const int l15 = lane & 15, hi = lane >> 4;

  f32x4 acc[2][4] = {};

  for (int k0 = 0; k0 < K; k0 += 64) {
#pragma unroll
    for (int rep = 0; rep < 2; ++rep) {
      int idx = tid + rep * 256;
      int row = idx >> 3, c8 = idx & 7;
      int cs = ((c8 ^ (row & 7)) << 3);
      __builtin_amdgcn_global_load_lds(
          (const __attribute__((address_space(1))) void*)(A + (size_t)(m0 + row) * K + k0 + cs),
          (__attribute__((address_space(3))) void*)(&As[idx * 8]), 16, 0, 0);
    }
#pragma unroll
    for (int rep = 0; rep < 4; ++rep) {
      int idx = tid + rep * 256;
      int row = idx >> 3, c8 = idx & 7;
      int cs = ((c8 ^ (row & 7)) << 3);
      __builtin_amdgcn_global_load_lds(
          (const __attribute__((address_space(1))) void*)(Bt + (size_t)(n0 + row) * K + k0 + cs),
          (__attribute__((address_space(3))) void*)(&Bs[idx * 8]), 16, 0, 0);
    }
    __syncthreads();
#pragma unroll
    for (int kk = 0; kk < 2; ++kk) {
      int kb = (kk * 32 + (hi << 3)) << 1;
      bf16x8 af[2], bfr[4];
#pragma unroll
      for (int mf = 0; mf < 2; ++mf) {
        int m = wr + mf * 16 + l15;
        af[mf] = *(const bf16x8*)((const char*)As + m * 128 + (kb ^ ((m & 7) << 4)));
      }
#pragma unroll
      for (int nf = 0; nf < 4; ++nf) {
        int n = wc + nf * 16 + l15;
        bfr[nf] = *(const bf16x8*)((const char*)Bs + n * 128 + (kb ^ ((n & 7) << 4)));
      }
#pragma unroll
      for (int mf = 0; mf < 2; ++mf)
#pragma unroll
        for (int nf = 0; nf < 4; ++nf)
          acc[mf][nf] = __builtin_amdgcn_mfma_f32_16x16x32_bf16(af[mf], bfr[nf], acc[mf][nf], 0, 0, 0);
    }
    __syncthreads();
  }

#pragma unroll
  for (int mf = 0; mf < 2; ++mf)
#pragma unroll
    for (int nf = 0; nf < 4; ++nf) {
      int col = n0 + wc + nf * 16 + l15;
      const bool isV = (col >= 256);
      float bia = isV ? biasV[col - 256] : biasK[col];
      u16x4 tv;
#pragma unroll
      for (int r = 0; r < 4; ++r) {
        int row = m0 + wr + mf * 16 + (hi << 2) + r;
        float val = acc[mf][nf][r] + bia;
        if (!isV) qkbf[(size_t)row * 256 + col] = f2bf(val);
        tv[r] = f2bf(val);
      }
      if (isV) {
        int row0 = m0 + wr + mf * 16 + (hi << 2);
        int vc = col - 256;
        size_t addr = (((size_t)(row0 >> 10) * 8 + (vc >> 5)) * 32 + (vc & 31)) * 1024 + (row0 & 1023);
        *(u16x4*)(vT + addr) = tv;
      }
    }
}

// ---------------------------------------------------------------------------
// Fused GEMM + bias + residual + LayerNorm. Tile 32(M) x 256(N=full row).
// z = blockIdx.y selects layer slab (A/Bt/bias/g/b strided; res/out pairs).
// ---------------------------------------------------------------------------
__global__ __launch_bounds__(256) void gemm_ln_kernel(
    const u16* __restrict__ Abase, const u16* __restrict__ BtBase,
    const float* __restrict__ biasBase, const float* __restrict__ res0,
    const float* __restrict__ res1, const float* __restrict__ gBase,
    const float* __restrict__ bBase, float* __restrict__ outf0,
    float* __restrict__ outf1, u16* __restrict__ outb0,
    u16* __restrict__ outb1, int K) {
  __shared__ u16 As[32 * 64];    // 4 KB
  __shared__ u16 Bs[256 * 64];   // 32 KB
  __shared__ float red[2][32][2];

  const int z = blockIdx.y;
  const u16* A = Abase + (size_t)z * LAYER_STRIDE;
  const u16* Bt = BtBase + (size_t)z * 65536;
  const float* bias = biasBase + z * 256;
  const float* res = z ? res1 : res0;
  const float* g = gBase + z * 256;
  const float* b = bBase + z * 256;
  float* outf = z ? outf1 : outf0;
  u16* outb = z ? outb1 : outb0;

  const int tid = threadIdx.x;
  const int lane = tid & 63;
  const int w = tid >> 6;
  const int rowgrp = w >> 1, colh = w & 1;
  const int m0 = blockIdx.x * 32;
  const int l15 = lane & 15, hi = lane >> 4;

  f32x4 acc[8] = {};

  for (int k0 = 0; k0 < K; k0 += 64) {
    {
      int row = tid >> 3, c8 = tid & 7;
      int cs = ((c8 ^ (row & 7)) << 3);
      __builtin_amdgcn_global_load_lds(
          (const __attribute__((address_space(1))) void*)(A + (size_t)(m0 + row) * K + k0 + cs),
          (__attribute__((address_space(3))) void*)(&As[tid * 8]), 16, 0, 0);
    }
#pragma unroll
    for (int rep = 0; rep < 8; ++rep) {
      int idx = tid + rep * 256;
      int row = idx >> 3, c8 = idx & 7;
      int cs = ((c8 ^ (row & 7)) << 3);
      __builtin_amdgcn_global_load_lds(
          (const __attribute__((address_space(1))) void*)(Bt + (size_t)row * K + k0 + cs),
          (__attribute__((address_space(3))) void*)(&Bs[idx * 8]), 16, 0, 0);
    }
    __syncthreads();
#pragma unroll
    for (int kk = 0; kk < 2; ++kk) {
      int kb = (kk * 32 + (hi << 3)) << 1;
      int m = rowgrp * 16 + l15;
      bf16x8 af = *(const bf16x8*)((const char*)As + m * 128 + (kb ^ ((m & 7) << 4)));
      bf16x8 bfr[8];
#pragma unroll
      for (int nf = 0; nf < 8; ++nf) {
        int n = colh * 128 + nf * 16 + l15;
        bfr[nf] = *(const bf16x8*)((const char*)Bs + n * 128 + (kb ^ ((n & 7) << 4)));
      }
#pragma unroll
      for (int nf = 0; nf < 8; ++nf)
        acc[nf] = __builtin_amdgcn_mfma_f32_16x16x32_bf16(af, bfr[nf], acc[nf], 0, 0, 0);
    }
    __syncthreads();
  }

  // ---- epilogue: bias + residual, then LN over the 256-col rows ----
  const int rbase = m0 + rowgrp * 16 + hi * 4;
  float s[4] = {0.f, 0.f, 0.f, 0.f}, ss[4] = {0.f, 0.f, 0.f, 0.f};
#pragma unroll
  for (int nf = 0; nf < 8; ++nf) {
    int col = colh * 128 + nf * 16 + l15;
    float bia = bias[col];
#pragma unroll
    for (int r = 0; r < 4; ++r) {
      float v = acc[nf][r] + bia + res[(size_t)(rbase + r) * 256 + col];
      acc[nf][r] = v;
      s[r] += v;
      ss[r] += v * v;
    }
  }
#pragma unroll
  for (int r = 0; r < 4; ++r) {
#pragma unroll
    for (int o = 1; o < 16; o <<= 1) {
      s[r] += __shfl_xor(s[r], o);
      ss[r] += __shfl_xor(ss[r], o);
    }
  }
  if (l15 == 0) {
#pragma unroll
    for (int r = 0; r < 4; ++r) {
      red[colh][rowgrp * 16 + hi * 4 + r][0] = s[r];
      red[colh][rowgrp * 16 + hi * 4 + r][1] = ss[r];
    }
  }
  __syncthreads();
  float mu[4], rs[4];
#pragma unroll
  for (int r = 0; r < 4; ++r) {
    int rr = rowgrp * 16 + hi * 4 + r;
    float S = red[0][rr][0] + red[1][rr][0];
    float SS = red[0][rr][1] + red[1][rr][1];
    mu[r] = S * (1.f / 256.f);
    float var = SS * (1.f / 256.f) - mu[r] * mu[r];
    rs[r] = rsqrtf(var + 1e-5f);
  }
#pragma unroll
  for (int nf = 0; nf < 8; ++nf) {
    int col = colh * 128 + nf * 16 + l15;
    float gv = g[col], bv = b[col];
#pragma unroll
    for (int r = 0; r < 4; ++r) {
      float o = (acc[nf][r] - mu[r]) * rs[r] * gv + bv;
      size_t addr = (size_t)(rbase + r) * 256 + col;
      outf[addr] = o;
      outb[addr] = f2bf(o);
    }
  }
}

// ---------------------------------------------------------------------------
// MFMA distance-decay attention (validated structure), z-merged over layers.
// ---------------------------------------------------------------------------
__global__ __launch_bounds__(256) void attn_mfma_kernel(
    const u16* __restrict__ qk2, const u16* __restrict__ vT2,
    u16* __restrict__ ao2, const float* __restrict__ gamBase, int excl) {
  __shared__ float zbuf[4][16];
  __shared__ float z2buf[4][16];
  __shared__ float accbuf[8][4][64];

  const int z = blockIdx.z;
  const u16* qkbf = qk2 + (size_t)z * LAYER_STRIDE;
  const u16* vT = vT2 + (size_t)z * LAYER_STRIDE;
  u16* ao = ao2 + (size_t)z * LAYER_STRIDE;
  const float* gam = gamBase + z * 8;

  const int lane = threadIdx.x & 63, w = threadIdx.x >> 6;
  const int qt = 63 - blockIdx.y;  // big-work blocks dispatch first
  const int bh = blockIdx.x;
  const int b = bh >> 3, h = bh & 7;
  const int q0 = qt * 16;
  const int l15 = lane & 15, hi = lane >> 4;
  const int i = q0 + l15;
  const float LOG2E = 1.4426950408889634f;
  const float g2 = -log1pf(__expf(gam[h])) * LOG2E;
  const float cscale = 0.17677669529663687f * LOG2E;
  const float CLIP2 = -16.609640474436812f;

  const u16* kbase = qkbf + (size_t)b * 1024 * 256 + h * 32;
  const u16* vbase = vT + (size_t)bh * 32 * 1024;
  const bf16x8 qfrag = *(const bf16x8*)(kbase + (size_t)i * 256 + hi * 8);

  const int mylim = i - excl;
  const int jmax = q0 + 15 - excl;
  const int ntiles = (jmax >> 4) + 1;
  const int C = (ntiles + 3) >> 2;
  const int c0 = w * C;
  const int tEnd = (c0 + C < ntiles) ? (c0 + C) : ntiles;
  const int count = (tEnd > c0) ? (tEnd - c0) : 0;

  auto calc_l = [&](int t, float* l) {
    bf16x8 kf = *(const bf16x8*)(kbase + (size_t)(t * 16 + l15) * 256 + hi * 8);
    f32x4 sA = {};
    sA = __builtin_amdgcn_mfma_f32_16x16x32_bf16(kf, qfrag, sA, 0, 0, 0);
    l[0] = sA[0] * cscale; l[1] = sA[1] * cscale;
    l[2] = sA[2] * cscale; l[3] = sA[3] * cscale;
    if (t == ntiles - 1) {
      const int kb = t * 16 + hi * 4;
      l[0] = (kb + 0 <= mylim) ? l[0] : -1000.f;
      l[1] = (kb + 1 <= mylim) ? l[1] : -1000.f;
      l[2] = (kb + 2 <= mylim) ? l[2] : -1000.f;
      l[3] = (kb + 3 <= mylim) ? l[3] : -1000.f;
    }
  };

  float zacc = 0.f;
  for (int t = c0; t < tEnd; ++t) {
    float l[4]; calc_l(t, l);
    zacc += (exp2f(l[0]) + exp2f(l[1])) + (exp2f(l[2]) + exp2f(l[3]));
  }
  zacc += __shfl_xor(zacc, 16);
  zacc += __shfl_xor(zacc, 32);
  if (lane < 16) zbuf[w][lane] = zacc;
  __syncthreads();

  const float zc0 = zbuf[0][l15], zc1 = zbuf[1][l15];
  const float zc2 = zbuf[2][l15], zc3 = zbuf[3][l15];
  const float Z = zc0 + zc1 + zc2 + zc3;
  const float invZ = Z > 0.f ? 1.f / Z : 0.f;
  float prefix = 0.f;
  if (w > 0) prefix += zc0;
  if (w > 1) prefix += zc1;
  if (w > 2) prefix += zc2;

  float carry = prefix, z2 = 0.f;
  f32x4 acc0 = {}, acc1 = {};

  auto sm4 = [&](const float* l, int kb) -> uint2 {
    const float e0 = exp2f(l[0]), e1 = exp2f(l[1]);
    const float e2 = exp2f(l[2]), e3 = exp2f(l[3]);
    const float cA = e0 + e1, cB2 = cA + e2, cC = cB2 + e3;
    float vsc = cC;
    float tmp = __shfl_up(vsc, 16); if (hi >= 1) vsc += tmp;
    tmp = __shfl_up(vsc, 32); if (hi >= 2) vsc += tmp;
    const float exg = vsc - cC;
    const float tot = __shfl(vsc, l15 + 48);
    const float cb = carry + exg;
    carry += tot;
    const float posb = (float)(i - kb);
    const float r0 = (Z - (cb + e0)) * invZ;
    const float r1 = (Z - (cb + cA)) * invZ;
    const float r2 = (Z - (cb + cB2)) * invZ;
    const float r3 = (Z - (cb + cC)) * invZ;
    const float d20 = fmaxf(r0 * posb, 0.f);
    const float d21 = fmaxf(r1 * (posb - 1.f), 0.f);
    const float d22 = fmaxf(r2 * (posb - 2.f), 0.f);
    const float d23 = fmaxf(r3 * (posb - 3.f), 0.f);
    const float a0 = fmaxf(__builtin_amdgcn_sqrtf(d20) * g2, CLIP2);
    const float a1 = fmaxf(__builtin_amdgcn_sqrtf(d21) * g2, CLIP2);
    const float a2 = fmaxf(__builtin_amdgcn_sqrtf(d22) * g2, CLIP2);
    const float a3 = fmaxf(__builtin_amdgcn_sqrtf(d23) * g2, CLIP2);
    const float p0 = exp2f(l[0] * exp2f(a0));
    const float p1 = exp2f(l[1] * exp2f(a1));
    const float p2 = exp2f(l[2] * exp2f(a2));
    const float p3 = exp2f(l[3] * exp2f(a3));
    z2 += (p0 + p1) + (p2 + p3);
    uint2 r; r.x = cvtpk_bf16(p0, p1); r.y = cvtpk_bf16(p2, p3);
    return r;
  };

  const int Cp = (count + 1) & ~1;
  for (int tl = 0; tl < Cp; tl += 2) {
    const int t0 = c0 + tl, t1 = t0 + 1;
    float la[4], lb[4];
    calc_l(t0, la);
    const bool v1 = (tl + 1 < count);
    if (v1) calc_l(t1, lb);
    const int jb = t0 * 16;
    bf16x8 vf0 = *(const bf16x8*)(vbase + (size_t)l15 * 1024 + jb + hi * 8);
    bf16x8 vf1 = *(const bf16x8*)(vbase + (size_t)(16 + l15) * 1024 + jb + hi * 8);
    uint2 uA = sm4(la, t0 * 16 + hi * 4);
    uint2 uB = make_uint2(0u, 0u);
    if (v1) uB = sm4(lb, t1 * 16 + hi * 4);
    const int srcA = l15 + (((2 * hi) & 3) << 4);
    const int srcB = l15 + (((2 * hi + 1) & 3) << 4);
    unsigned a00 = (unsigned)__shfl((int)uA.x, srcA);
    unsigned a01 = (unsigned)__shfl((int)uB.x, srcA);
    unsigned a10 = (unsigned)__shfl((int)uA.y, srcA);
    unsigned a11 = (unsigned)__shfl((int)uB.y, srcA);
    unsigned b00 = (unsigned)__shfl((int)uA.x, srcB);
    unsigned b01 = (unsigned)__shfl((int)uB.x, srcB);
    unsigned b10 = (unsigned)__shfl((int)uA.y, srcB);
    unsigned b11 = (unsigned)__shfl((int)uB.y, srcB);
    const bool up = hi >= 2;
    union { unsigned u[4]; bf16x8 v; } pf;
    pf.u[0] = up ? a01 : a00;
    pf.u[1] = up ? a11 : a10;
    pf.u[2] = up ? b01 : b00;
    pf.u[3] = up ? b11 : b10;
    acc0 = __builtin_amdgcn_mfma_f32_16x16x32_bf16(vf0, pf.v, acc0, 0, 0, 0);
    acc1 = __builtin_amdgcn_mfma_f32_16x16x32_bf16(vf1, pf.v, acc1, 0, 0, 0);
  }

  z2 += __shfl_xor(z2, 16);
  z2 += __shfl_xor(z2, 32);
  if (lane < 16) z2buf[w][lane] = z2;
#pragma unroll
  for (int j = 0; j < 4; ++j) {
    accbuf[j][w][lane] = acc0[j];
    accbuf[4 + j][w][lane] = acc1[j];
  }
  __syncthreads();

  if (w == 0) {
    const float z2t = z2buf[0][l15] + z2buf[1][l15] + z2buf[2][l15] + z2buf[3][l15];
    const float inv2 = z2t > 0.f ? 1.f / z2t : 0.f;
    u16* aop = ao + ((size_t)(b * 1024 + i)) * 256 + h * 32;
    float s0[4], s1[4];
#pragma unroll
    for (int j = 0; j < 4; ++j) {
      s0[j] = (accbuf[j][0][lane] + accbuf[j][1][lane] + accbuf[j][2][lane] + accbuf[j][3][lane]) * inv2;
      s1[j] = (accbuf[4 + j][0][lane] + accbuf[4 + j][1][lane] + accbuf[4 + j][2][lane] + accbuf[4 + j][3][lane]) * inv2;
    }
    uint2 o0, o1;
    o0.x = cvtpk_bf16(s0[0], s0[1]); o0.y = cvtpk_bf16(s0[2], s0[3]);
    o1.x = cvtpk_bf16(s1[0], s1[1]); o1.y = cvtpk_bf16(s1[2], s1[3]);
    *(uint2*)(aop + hi * 4) = o0;
    *(uint2*)(aop + 16 + hi * 4) = o1;
  }
}

// ---------------------------------------------------------------------------
// One-shot prep: all 5 weight transposes + both input casts.
// ---------------------------------------------------------------------------
__global__ __launch_bounds__(256) void prep_kernel(
    const float* __restrict__ Wk, const float* __restrict__ Wv,
    const float* __restrict__ Wo, const float* __restrict__ W1,
    const float* __restrict__ W2, const float* __restrict__ qe,
    const float* __restrict__ qae, u16* __restrict__ Wkvt,
    u16* __restrict__ Wot, u16* __restrict__ W1t, u16* __restrict__ W2t,
    u16* __restrict__ xbf, u16* __restrict__ ybf) {
  __shared__ float t[32][33];
  const int bid = blockIdx.x;
  const int tx = threadIdx.x, ty = threadIdx.y;

  if (bid < 2112) {
    const float* src; u16* dst;
    int K, N, n0, k0;
    size_t so, doff;
    if (bid < 576) {
      int wsel = bid / 192, r = bid % 192, z = r >> 6, tt = r & 63;
      K = 256; N = 256;
      n0 = (tt & 7) * 32; k0 = (tt >> 3) * 32;
      so = (size_t)z * 65536;
      if (wsel == 0)      { src = Wk; dst = Wkvt;        doff = (size_t)z * 131072; }
      else if (wsel == 1) { src = Wv; dst = Wkvt + 65536; doff = (size_t)z * 131072; }
      else                { src = Wo; dst = Wot;          doff = (size_t)z * 65536; }
    } else if (bid < 1344) {
      int r = bid - 576, z = r >> 8, tt = r & 255;
      K = 256; N = 1024;
      n0 = (tt & 31) * 32; k0 = (tt >> 5) * 32;
      src = W1; dst = W1t;
      so = (size_t)z * 262144; doff = (size_t)z * 262144;
    } else {
      int r = bid - 1344, z = r >> 8, tt = r & 255;
      K = 1024; N = 256;
      n0 = (tt & 7) * 32; k0 = (tt >> 3) * 32;
      src = W2; dst = W2t;
      so = (size_t)z * 262144; doff = (size_t)z * 262144;
    }
#pragma unroll
    for (int r = 0; r < 32; r += 8)
      t[ty + r][tx] = src[so + (size_t)(k0 + ty + r) * N + n0 + tx];
    __syncthreads();
#pragma unroll
    for (int r = 0; r < 32; r += 8)
      dst[doff + (size_t)(n0 + ty + r) * K + k0 + tx] = f2bf(t[tx][ty + r]);
  } else {
    int r = bid - 2112;  // 0..2047
    const float* in = (r < 1024) ? qe : qae;
    u16* out = (r < 1024) ? xbf : ybf;
    int rr = r & 1023;
    int tid = ty * 32 + tx;
    size_t i = ((size_t)rr * 256 + tid) * 8;
    float4 a = *(const float4*)(in + i);
    float4 c = *(const float4*)(in + i + 4);
    u16x8 o;
    o[0] = f2bf(a.x); o[1] = f2bf(a.y); o[2] = f2bf(a.z); o[3] = f2bf(a.w);
    o[4] = f2bf(c.x); o[5] = f2bf(c.y); o[6] = f2bf(c.z); o[7] = f2bf(c.w);
    *(u16x8*)(out + i) = o;
  }
}

// ---------------------------------------------------------------------------
extern "C" void kernel_launch(void* const* d_in, const int* in_sizes, int n_in,
                              void* d_out, int out_size, void* d_ws,
                              size_t ws_size, hipStream_t stream) {
  const float* q_embed = (const float*)d_in[0];
  const float* qa_embed = (const float*)d_in[1];
  const float* Wk = (const float*)d_in[2];
  const float* bk = (const float*)d_in[3];
  const float* Wv = (const float*)d_in[4];
  const float* bv = (const float*)d_in[5];
  const float* Wo = (const float*)d_in[6];
  const float* bo = (const float*)d_in[7];
  const float* gammas = (const float*)d_in[8];
  const float* ln1_g = (const float*)d_in[9];
  const float* ln1_b = (const float*)d_in[10];
  const float* W1 = (const float*)d_in[11];
  const float* b1 = (const float*)d_in[12];
  const float* W2 = (const float*)d_in[13];
  const float* b2 = (const float*)d_in[14];
  const float* ln2_g = (const float*)d_in[15];
  const float* ln2_b = (const float*)d_in[16];

  const size_t ACT_F32 = (size_t)8192 * 256 * 4;  // 8 MB
  const size_t ACT_BF = (size_t)8192 * 256 * 2;   // 4 MB
  char* p = (char*)d_ws;
  auto carve = [&](size_t bytes) {
    void* r = (void*)p;
    p += (bytes + 255) & ~(size_t)255;
    return r;
  };
  float* yb = (float*)carve(ACT_F32);
  float* xb = (float*)carve(ACT_F32);
  u16* xbf = (u16*)carve(ACT_BF);
  u16* ybf = (u16*)carve(ACT_BF);
  u16* qk2 = (u16*)carve(2 * ACT_BF);
  u16* vT2 = (u16*)carve(2 * ACT_BF);
  u16* ao2 = (u16*)carve(2 * ACT_BF);
  u16* hbf = (u16*)carve((size_t)8192 * 1024 * 2);  // 16 MB
  u16* Wkvt = (u16*)carve((size_t)3 * 131072 * 2);
  u16* Wot = (u16*)carve((size_t)3 * 65536 * 2);
  u16* W1t = (u16*)carve((size_t)3 * 262144 * 2);
  u16* W2t = (u16*)carve((size_t)3 * 262144 * 2);

  prep_kernel<<<4160, dim3(32, 8), 0, stream>>>(
      Wk, Wv, Wo, W1, W2, q_embed, qa_embed, Wkvt, Wot, W1t, W2t, xbf, ybf);

  // ---- layers 0 (y-chain) + 1 (x-chain) merged: independent until block 2 ----
  gemm_kv_kernel<<<dim3(128, 4, 2), 256, 0, stream>>>(
      ybf, ybf, xbf, xbf, Wkvt, bk, bv, qk2, vT2);
  attn_mfma_kernel<<<dim3(64, 64, 2), 256, 0, stream>>>(qk2, vT2, ao2, gammas, 0);
  gemm_ln_kernel<<<dim3(256, 2), 256, 0, stream>>>(
      ao2, Wot, bo, qa_embed, q_embed, ln1_g, ln1_b, yb, xb, ybf, xbf, 256);
  // block 0 FFN tail
  gemm_w_kernel<1><<<dim3(128, 8), 256, 0, stream>>>(ybf, W1t, b1, hbf, 8192, 1024, 256);
  gemm_ln_kernel<<<dim3(256, 1), 256, 0, stream>>>(
      hbf, W2t, b2, yb, yb, ln2_g, ln2_b, yb, yb, ybf, ybf, 1024);

  // ---- block 2: K from x, V from y (post-FFN), excl mask (zero_pad natural) ----
  gemm_kv_kernel<<<dim3(128, 4, 1), 256, 0, stream>>>(
      xbf, ybf, xbf, ybf, Wkvt + 262144, bk + 512, bv + 512, qk2, vT2);
  attn_mfma_kernel<<<dim3(64, 64, 1), 256, 0, stream>>>(qk2, vT2, ao2, gammas + 16, 1);
  gemm_ln_kernel<<<dim3(256, 1), 256, 0, stream>>>(
      ao2, Wot + 131072, bo + 512, xb, xb, ln1_g + 512, ln1_b + 512, xb, xb, xbf, xbf, 256);
  gemm_w_kernel<1><<<dim3(128, 8), 256, 0, stream>>>(xbf, W1t + 524288, b1 + 2048, hbf, 8192, 1024, 256);
  gemm_ln_kernel<<<dim3(256, 1), 256, 0, stream>>>(
      hbf, W2t + 524288, b2 + 512, xb, xb, ln2_g + 512, ln2_b + 512, (float*)d_out, (float*)d_out, xbf, xbf, 1024);
}